// Round 1
// baseline (611.646 us; speedup 1.0000x reference)
//
#include <hip/hip_runtime.h>
#include <math.h>

// Graph VAE forward, bf16 edition.
//   SpMM at the narrow dim (gconv2 does GEMM first), pull-style padded CSR.
//   All feature-map intermediates bf16 (fp32 accumulate):
//     features->xb --spmm--> agg1 --MFMA--> h(bf16, in d_out)
//     --MFMA--> hw --spmm+epi--> mean/logvar(fp32 out), z(bf16)
//     --spmm--> aggz --MFMA--> recon(fp32 out)
//   CSR build (this round): two-phase bucketed scatter.
//     Phase A (k_bucket): coalesced edge pass -> 8 dst-range buckets of packed
//       (dst,src) u64 records, LDS-aggregated chunk reservation (streaming writes).
//     Phase B (k_fill): bucket b handled by blocks with blockIdx%8==b (XCD-pinned);
//       scatter target is a 3.2MB ebuf slice + 50KB cnt slice -> L2-resident,
//       line writes merge in L2 instead of 1 HBM transaction per edge.

#define MAXD 64   // padded per-node in-edge capacity; deg ~ Poisson(16)
#define NB 8      // dst-range buckets (== XCD count)

typedef short short8 __attribute__((ext_vector_type(8)));
typedef float f32x4 __attribute__((ext_vector_type(4)));

__device__ __forceinline__ unsigned short f2bf(float f) {
  union { float f; unsigned u; } c; c.f = f;
  unsigned r = c.u + 0x7FFF + ((c.u >> 16) & 1);   // RNE
  return (unsigned short)(r >> 16);
}
__device__ __forceinline__ float bf2f(unsigned short b) {
  return __builtin_bit_cast(float, (unsigned)b << 16);
}

// ---- phase A: bucket edges by dst range + out-degree histogram ---------
__global__ __launch_bounds__(256) void k_bucket(const int* __restrict__ src,
    const int* __restrict__ dst, int* __restrict__ degout, int* __restrict__ bcnt,
    unsigned long long* __restrict__ bkt, int E, float bscale, int cap) {
  __shared__ int lc[4][NB];
  __shared__ int lb[4][NB];
  int tid = threadIdx.x;
  int wv = tid >> 6;
  if (tid < 4 * NB) ((int*)lc)[tid] = 0;
  __syncthreads();

  int e0 = (blockIdx.x * 256 + tid) * 4;
  int nv = E - e0; nv = nv < 0 ? 0 : (nv > 4 ? 4 : nv);
  int s[4], d[4], b[4], p[4];
  if (nv == 4) {
    int4 s4 = *(const int4*)(src + e0);
    int4 d4 = *(const int4*)(dst + e0);
    s[0] = s4.x; s[1] = s4.y; s[2] = s4.z; s[3] = s4.w;
    d[0] = d4.x; d[1] = d4.y; d[2] = d4.z; d[3] = d4.w;
  } else {
    for (int j = 0; j < nv; j++) { s[j] = src[e0 + j]; d[j] = dst[e0 + j]; }
  }
  #pragma unroll
  for (int j = 0; j < 4; j++) {
    if (j < nv) {
      atomicAdd(&degout[s[j]], 1);
      int bb = (int)((float)d[j] * bscale);
      b[j] = bb < NB - 1 ? bb : NB - 1;
      p[j] = atomicAdd(&lc[wv][b[j]], 1);
    }
  }
  __syncthreads();
  if (tid < NB) {
    int t0 = lc[0][tid], t1 = lc[1][tid], t2 = lc[2][tid], t3 = lc[3][tid];
    int base = atomicAdd(&bcnt[tid], t0 + t1 + t2 + t3);
    lb[0][tid] = base;
    lb[1][tid] = base + t0;
    lb[2][tid] = base + t0 + t1;
    lb[3][tid] = base + t0 + t1 + t2;
  }
  __syncthreads();
  #pragma unroll
  for (int j = 0; j < 4; j++) {
    if (j < nv) {
      int pos = lb[wv][b[j]] + p[j];
      if (pos < cap)
        bkt[(size_t)b[j] * cap + pos] =
            ((unsigned long long)(unsigned)d[j] << 32) | (unsigned)s[j];
    }
  }
}

// ---- phase B: per-bucket CSR fill (scatter confined to one L2) ---------
__global__ __launch_bounds__(256) void k_fill(
    const unsigned long long* __restrict__ bkt, const int* __restrict__ bcnt,
    int* __restrict__ cnt, int* __restrict__ ebuf, int cap) {
  int b = blockIdx.x & (NB - 1);          // == XCD id (blockIdx % 8 heuristic)
  int cb = blockIdx.x >> 3;
  int m = bcnt[b]; m = m < cap ? m : cap;
  const unsigned long long* e = bkt + (size_t)b * cap;
  int stride = (gridDim.x >> 3) * 256;
  for (int i = cb * 256 + (int)threadIdx.x; i < m; i += stride) {
    unsigned long long v = __builtin_nontemporal_load(e + i);
    int sN = (int)(unsigned)v;
    int dN = (int)(v >> 32);
    int p = atomicAdd(&cnt[dN], 1);
    if (p < MAXD) ebuf[(size_t)dN * MAXD + p] = sN;   // cached: merges in L2
  }
}

__global__ __launch_bounds__(256) void k_scale(const int* __restrict__ degout,
    const int* __restrict__ cnt, float* __restrict__ sout,
    float* __restrict__ sin_, int N) {
  int i = blockIdx.x * 256 + threadIdx.x;
  if (i >= N) return;
  int dO = degout[i]; if (dO < 1) dO = 1;
  int dI = cnt[i];    if (dI < 1) dI = 1;
  sout[i] = rsqrtf((float)dO);
  sin_[i] = rsqrtf((float)dI);
}

// ---- fp32 -> bf16 row-major convert (features) ------------------------
__global__ __launch_bounds__(256) void k_cvt(const float* __restrict__ in,
    unsigned short* __restrict__ out, int n) {
  int i = (blockIdx.x * 256 + threadIdx.x) * 4;
  if (i >= n) return;
  float4 f = *(const float4*)(in + i);
  unsigned lo = (unsigned)f2bf(f.x) | ((unsigned)f2bf(f.y) << 16);
  unsigned hi = (unsigned)f2bf(f.z) | ((unsigned)f2bf(f.w) << 16);
  uint2 o; o.x = lo; o.y = hi;
  *(uint2*)(out + i) = o;
}

// ---- repack W[K][OC] fp32 -> bf16 B-fragment layout -------------------
template <int K, int OC>
__global__ __launch_bounds__(256) void k_wrepack(const float* __restrict__ W,
    short* __restrict__ Wp) {
  constexpr int KC = K / 32;
  constexpr int TOT = (OC / 16) * KC * 64;
  int t = blockIdx.x * 256 + threadIdx.x;
  if (t >= TOT) return;
  int lane = t & 63;
  int kc = (t >> 6) % KC;
  int nt = t / (KC * 64);
  int n = nt * 16 + (lane & 15);
  int k0 = kc * 32 + ((lane >> 4) * 8);
  short8 v;
  #pragma unroll
  for (int j = 0; j < 8; j++) v[j] = (short)f2bf(W[(size_t)(k0 + j) * OC + n]);
  *(short8*)(Wp + (size_t)t * 8) = v;
}

// ---- MFMA GEMM: C[N,OC] = A[N,K](bf16) @ Wp(frag bf16) (+bias, relu) --
template <int K, int OC, bool RELU, bool BIAS, bool OUTBF16>
__global__ __launch_bounds__(256) void k_gemm_mfma(
    const unsigned short* __restrict__ A, const short* __restrict__ Wp,
    const float* __restrict__ bias, void* __restrict__ Cout, int N) {
  constexpr int KC = K / 32;
  constexpr int NT = OC / 16;
  int lane = threadIdx.x & 63;
  int wv = threadIdx.x >> 6;
  int m0 = (blockIdx.x * 4 + wv) * 16;
  if (m0 >= N) return;
  int mrow = m0 + (lane & 15);
  if (mrow >= N) mrow = N - 1;          // clamp loads; stores predicated
  int q = lane >> 4;
  short8 av[KC];
  #pragma unroll
  for (int kc = 0; kc < KC; kc++)
    av[kc] = *(const short8*)(A + (size_t)mrow * K + kc * 32 + q * 8);
  int col0 = lane & 15;
  int rbase = m0 + q * 4;               // C/D: col=lane&15, row=(lane>>4)*4+r
  #pragma unroll
  for (int nt = 0; nt < NT; nt++) {
    f32x4 acc = {0.f, 0.f, 0.f, 0.f};
    #pragma unroll
    for (int kc = 0; kc < KC; kc++) {
      short8 bv = *(const short8*)(Wp + ((size_t)(nt * KC + kc) * 64 + lane) * 8);
      acc = __builtin_amdgcn_mfma_f32_16x16x32_bf16(av[kc], bv, acc, 0, 0, 0);
    }
    int col = nt * 16 + col0;
    float bb = BIAS ? bias[col] : 0.f;
    #pragma unroll
    for (int r = 0; r < 4; r++) {
      int row = rbase + r;
      if (row < N) {
        float v = acc[r] + bb;
        if (RELU) v = fmaxf(v, 0.f);
        if (OUTBF16) ((unsigned short*)Cout)[(size_t)row * OC + col] = f2bf(v);
        else         ((float*)Cout)[(size_t)row * OC + col] = v;
      }
    }
  }
}

// ---- SpMM (pull) dim=128 bf16: out[v] = s_in[v]*sum s_out[u]*x[u] -----
__global__ __launch_bounds__(256) void k_spmm128b(const unsigned short* __restrict__ x,
    const int* __restrict__ ebuf, const int* __restrict__ cnt,
    const float* __restrict__ sout, const float* __restrict__ sin_,
    unsigned short* __restrict__ out, int N) {
  int lane = threadIdx.x & 63;
  int v = blockIdx.x * 4 + (threadIdx.x >> 6);
  if (v >= N) return;
  v = __builtin_amdgcn_readfirstlane(v);
  int c = cnt[v]; c = c < MAXD ? c : MAXD;
  const int* el = ebuf + (size_t)v * MAXD;
  int u_l = 0; float w_l = 0.f;
  if (lane < c) { u_l = el[lane]; w_l = sout[u_l]; }
  float ax = 0.f, ay = 0.f;
  int i = 0;
  for (; i + 4 <= c; i += 4) {
    #pragma unroll
    for (int j = 0; j < 4; j++) {
      int u = __shfl(u_l, i + j);
      float w = __shfl(w_l, i + j);
      unsigned p = *(const unsigned*)(x + (size_t)u * 128 + lane * 2);
      float lo = __builtin_bit_cast(float, p << 16);
      float hi = __builtin_bit_cast(float, p & 0xFFFF0000u);
      ax = fmaf(w, lo, ax); ay = fmaf(w, hi, ay);
    }
  }
  for (; i < c; i++) {
    int u = __shfl(u_l, i);
    float w = __shfl(w_l, i);
    unsigned p = *(const unsigned*)(x + (size_t)u * 128 + lane * 2);
    float lo = __builtin_bit_cast(float, p << 16);
    float hi = __builtin_bit_cast(float, p & 0xFFFF0000u);
    ax = fmaf(w, lo, ax); ay = fmaf(w, hi, ay);
  }
  float sv = sin_[v];
  unsigned o = (unsigned)f2bf(sv * ax) | ((unsigned)f2bf(sv * ay) << 16);
  *(unsigned*)(out + (size_t)v * 128 + lane * 2) = o;
}

// ---- SpMM dim=128 bf16 + epilogue: +b2, split, z(bf16) ----------------
__global__ __launch_bounds__(256) void k_spmm2b(const unsigned short* __restrict__ hw,
    const int* __restrict__ ebuf, const int* __restrict__ cnt,
    const float* __restrict__ sout, const float* __restrict__ sin_,
    const float* __restrict__ b2, const float* __restrict__ eps,
    float* __restrict__ mean_out, float* __restrict__ logvar_out,
    unsigned short* __restrict__ z, int N) {
  int lane = threadIdx.x & 63;
  int v = blockIdx.x * 4 + (threadIdx.x >> 6);
  if (v >= N) return;
  v = __builtin_amdgcn_readfirstlane(v);
  int c = cnt[v]; c = c < MAXD ? c : MAXD;
  const int* el = ebuf + (size_t)v * MAXD;
  int u_l = 0; float w_l = 0.f;
  if (lane < c) { u_l = el[lane]; w_l = sout[u_l]; }
  float ax = 0.f, ay = 0.f;
  int i = 0;
  for (; i + 4 <= c; i += 4) {
    #pragma unroll
    for (int j = 0; j < 4; j++) {
      int u = __shfl(u_l, i + j);
      float w = __shfl(w_l, i + j);
      unsigned p = *(const unsigned*)(hw + (size_t)u * 128 + lane * 2);
      float lo = __builtin_bit_cast(float, p << 16);
      float hi = __builtin_bit_cast(float, p & 0xFFFF0000u);
      ax = fmaf(w, lo, ax); ay = fmaf(w, hi, ay);
    }
  }
  for (; i < c; i++) {
    int u = __shfl(u_l, i);
    float w = __shfl(w_l, i);
    unsigned p = *(const unsigned*)(hw + (size_t)u * 128 + lane * 2);
    float lo = __builtin_bit_cast(float, p << 16);
    float hi = __builtin_bit_cast(float, p & 0xFFFF0000u);
    ax = fmaf(w, lo, ax); ay = fmaf(w, hi, ay);
  }
  float sv = sin_[v];
  float2 bb = ((const float2*)b2)[lane];
  float mx = fmaf(sv, ax, bb.x);
  float my = fmaf(sv, ay, bb.y);
  // lanes 0..31: mean cols (2l,2l+1); lanes 32..63: logvar cols
  if (lane < 32) ((float2*)mean_out)[(size_t)v * 32 + lane] = make_float2(mx, my);
  else           ((float2*)logvar_out)[(size_t)v * 32 + (lane - 32)] = make_float2(mx, my);
  float lx = __shfl(mx, (lane & 31) + 32);
  float ly = __shfl(my, (lane & 31) + 32);
  if (lane < 32) {
    float2 e2 = ((const float2*)eps)[(size_t)v * 32 + lane];
    float zx = fmaf(e2.x, expf(0.5f * lx), mx);
    float zy = fmaf(e2.y, expf(0.5f * ly), my);
    unsigned o = (unsigned)f2bf(zx) | ((unsigned)f2bf(zy) << 16);
    *(unsigned*)(z + (size_t)v * 64 + lane * 2) = o;
  }
}

// ---- SpMM dim=64 bf16: aggz[v] = s_in[v]*sum s_out[u]*z[u] ------------
__global__ __launch_bounds__(256) void k_spmm64b(const unsigned short* __restrict__ z,
    const int* __restrict__ ebuf, const int* __restrict__ cnt,
    const float* __restrict__ sout, const float* __restrict__ sin_,
    unsigned short* __restrict__ aggz, int N) {
  int lane = threadIdx.x & 63;
  int v = blockIdx.x * 4 + (threadIdx.x >> 6);
  if (v >= N) return;
  v = __builtin_amdgcn_readfirstlane(v);
  int c = cnt[v]; c = c < MAXD ? c : MAXD;
  const int* el = ebuf + (size_t)v * MAXD;
  int u_l = 0; float w_l = 0.f;
  if (lane < c) { u_l = el[lane]; w_l = sout[u_l]; }
  float a = 0.f;
  int i = 0;
  for (; i + 8 <= c; i += 8) {
    #pragma unroll
    for (int j = 0; j < 8; j++) {
      int u = __shfl(u_l, i + j);
      float w = __shfl(w_l, i + j);
      a = fmaf(w, bf2f(z[(size_t)u * 64 + lane]), a);
    }
  }
  for (; i < c; i++) {
    int u = __shfl(u_l, i);
    float w = __shfl(w_l, i);
    a = fmaf(w, bf2f(z[(size_t)u * 64 + lane]), a);
  }
  aggz[(size_t)v * 64 + lane] = f2bf(sin_[v] * a);
}

extern "C" void kernel_launch(void* const* d_in, const int* in_sizes, int n_in,
                              void* d_out, int out_size, void* d_ws, size_t ws_size,
                              hipStream_t stream) {
  const float* features = (const float*)d_in[0];
  const int*   src      = (const int*)d_in[1];
  const int*   dst      = (const int*)d_in[2];
  const float* eps      = (const float*)d_in[3];
  const float* W1       = (const float*)d_in[4];
  const float* b1       = (const float*)d_in[5];
  const float* W2       = (const float*)d_in[6];
  const float* b2       = (const float*)d_in[7];
  const float* W3       = (const float*)d_in[8];
  const float* b3       = (const float*)d_in[9];
  const int E = in_sizes[1];
  const int N = in_sizes[3] / 64;   // eps is N x 64
  float* out = (float*)d_out;

  // workspace (~78 MB): two aliased N*256-byte feature regions
  char* ws = (char*)d_ws;
  int* degout = (int*)ws;            ws += (size_t)N * 4;
  int* cnt    = (int*)ws;            ws += (size_t)N * 4;
  int* bcnt   = (int*)ws;            ws += 32;              // NB bucket counters
  int* ebuf   = (int*)ws;            ws += (size_t)N * MAXD * 4;
  float* sout = (float*)ws;          ws += (size_t)N * 4;
  float* sin_ = (float*)ws;          ws += (size_t)N * 4;
  short* W1p  = (short*)ws;          ws += 128 * 256 * 2;
  short* W2p  = (short*)ws;          ws += 256 * 128 * 2;
  short* W3p  = (short*)ws;          ws += 64 * 128 * 2;
  char* R1    = ws;                  ws += (size_t)N * 256;  // xb -> hwb -> aggz
  char* R2    = ws;                  ws += (size_t)N * 256;  // bkt -> agg1 -> z

  unsigned short* xb    = (unsigned short*)R1;  // N x 128 bf16
  unsigned short* hwb   = (unsigned short*)R1;  // N x 128 bf16 (xb dead)
  unsigned short* aggzb = (unsigned short*)R1;  // N x 64  bf16 (hwb dead)
  unsigned short* agg1b = (unsigned short*)R2;  // N x 128 bf16
  unsigned short* zb    = (unsigned short*)R2;  // N x 64  bf16 (agg1 dead)
  // bucket records (NB*cap*8B ~ 13MB) alias R2: dead before agg1b is written
  unsigned long long* bkt = (unsigned long long*)R2;
  const int cap = (E + NB - 1) / NB + 4096;

  // h (N x 256 bf16 = 51.2MB) lives in out[0..128N) floats; dead before recon
  unsigned short* h     = (unsigned short*)out;
  float* recon          = out;
  float* mean_out       = out + (size_t)N * 128;
  float* logvar_out     = out + (size_t)N * 192;

  hipMemsetAsync(degout, 0, (size_t)N * 8 + 32, stream);  // degout + cnt + bcnt

  k_bucket<<<((E + 3) / 4 + 255) / 256, 256, 0, stream>>>(
      src, dst, degout, bcnt, bkt, E, (float)NB / (float)N, cap);
  k_fill<<<NB * 128, 256, 0, stream>>>(bkt, bcnt, cnt, ebuf, cap);
  k_scale<<<(N + 255) / 256, 256, 0, stream>>>(degout, cnt, sout, sin_, N);
  k_cvt<<<((N * 128 / 4) + 255) / 256, 256, 0, stream>>>(features, xb, N * 128);
  k_wrepack<128, 256><<<16, 256, 0, stream>>>(W1, W1p);
  k_wrepack<256, 128><<<16, 256, 0, stream>>>(W2, W2p);
  k_wrepack<64, 128><<<4, 256, 0, stream>>>(W3, W3p);

  // gconv1: SpMM(xb) -> agg1b; MFMA GEMM 128->256 +b1, relu -> h (bf16)
  k_spmm128b<<<(N + 3) / 4, 256, 0, stream>>>(xb, ebuf, cnt, sout, sin_, agg1b, N);
  k_gemm_mfma<128, 256, true, true, true>
      <<<(N + 63) / 64, 256, 0, stream>>>(agg1b, W1p, b1, h, N);

  // gconv2: MFMA GEMM 256->128 (h @ W2 -> hwb), then SpMM +b2, split, z(bf16)
  k_gemm_mfma<256, 128, false, false, true>
      <<<(N + 63) / 64, 256, 0, stream>>>(h, W2p, nullptr, hwb, N);
  k_spmm2b<<<(N + 3) / 4, 256, 0, stream>>>(hwb, ebuf, cnt, sout, sin_, b2, eps,
                                            mean_out, logvar_out, zb, N);

  // gconv3: SpMM(zb) -> aggzb (bf16); MFMA GEMM 64->128 +b3 -> recon
  k_spmm64b<<<(N + 3) / 4, 256, 0, stream>>>(zb, ebuf, cnt, sout, sin_, aggzb, N);
  k_gemm_mfma<64, 128, false, true, false>
      <<<(N + 63) / 64, 256, 0, stream>>>(aggzb, W3p, b3, recon, N);
}

// Round 3
// 541.227 us; speedup vs baseline: 1.1301x; 1.1301x over previous
//
#include <hip/hip_runtime.h>
#include <math.h>

// Graph VAE forward, bf16 edition.
//   SpMM at the narrow dim (gconv2 does GEMM first), pull-style padded CSR.
//   All feature-map intermediates bf16 (fp32 accumulate):
//     features->xb --spmm--> agg1 --MFMA--> h(bf16, in d_out)
//     --MFMA--> hw --spmm+epi--> mean/logvar(fp32 out), z(bf16)
//     --spmm--> aggz --MFMA--> recon(fp32 out)
//   CSR build: NO per-edge global atomics.
//     k_bucket2: per-WG LDS counting into 391 fine buckets (256 nodes each),
//       chunk reservation (~300K atomic-returns total vs 3.2M per-edge),
//       4B packed (dl,s) records by dst + 1B records by src.
//     k_csr: one WG owns one fine bucket; LDS-atomic slot assignment,
//       ebuf scatter confined to 64KB, cnt written coalesced.
//     k_deg: per-bucket LDS histogram of src records -> degout.

#define MAXD 64   // padded per-node in-edge capacity; deg ~ Poisson(16)
#define FBSH 8    // 256 nodes per fine bucket (== blockDim of k_csr/k_deg)
#define EPT  16   // edges per thread in k_bucket2 (4096 per WG)

typedef short short8 __attribute__((ext_vector_type(8)));
typedef float f32x4 __attribute__((ext_vector_type(4)));

__device__ __forceinline__ unsigned short f2bf(float f) {
  union { float f; unsigned u; } c; c.f = f;
  unsigned r = c.u + 0x7FFF + ((c.u >> 16) & 1);   // RNE
  return (unsigned short)(r >> 16);
}
__device__ __forceinline__ float bf2f(unsigned short b) {
  return __builtin_bit_cast(float, (unsigned)b << 16);
}

// ---- phase A: two-level bucket, all per-edge counting in LDS -----------
__global__ __launch_bounds__(256) void k_bucket2(const int* __restrict__ src,
    const int* __restrict__ dst, int* __restrict__ bcd, int* __restrict__ bcs,
    int* __restrict__ bktd, unsigned char* __restrict__ srec,
    int E, int NFB, int cap2) {
  extern __shared__ int sh[];            // 4*NFB ints
  int* lcd = sh;                         // dst-bucket counts
  int* lbd = sh + NFB;                   // dst-bucket running offsets
  int* lcs = sh + 2 * NFB;               // src-bucket counts
  int* lbs = sh + 3 * NFB;               // src-bucket running offsets
  int tid = threadIdx.x;
  for (int i = tid; i < 4 * NFB; i += 256) sh[i] = 0;
  __syncthreads();
  int e0 = blockIdx.x * (256 * EPT);
  // pass 1: count per fine bucket (LDS atomics only)
  #pragma unroll 4
  for (int j = 0; j < EPT; j++) {
    int e = e0 + j * 256 + tid;
    if (e < E) {
      int d = dst[e]; atomicAdd(&lcd[d >> FBSH], 1);
      int s = src[e]; atomicAdd(&lcs[s >> FBSH], 1);
    }
  }
  __syncthreads();
  // reserve global chunks: one atomic per (WG, touched bucket)
  for (int fb = tid; fb < NFB; fb += 256) {
    int c = lcd[fb];
    if (c) lbd[fb] = atomicAdd(&bcd[fb], c);
    int cs = lcs[fb];
    if (cs) lbs[fb] = atomicAdd(&bcs[fb], cs);
  }
  __syncthreads();
  // pass 2: re-read edges (L1/L2 hot), place records
  #pragma unroll 4
  for (int j = 0; j < EPT; j++) {
    int e = e0 + j * 256 + tid;
    if (e < E) {
      int d = dst[e]; int s = src[e];
      int fbd = d >> FBSH;
      int od = atomicAdd(&lbd[fbd], 1);
      if (od < cap2) bktd[(size_t)fbd * cap2 + od] = ((d & 255) << 24) | s;
      int fbs = s >> FBSH;
      int os = atomicAdd(&lbs[fbs], 1);
      if (os < cap2) srec[(size_t)fbs * cap2 + os] = (unsigned char)(s & 255);
    }
  }
}

// ---- phase C1: per-bucket CSR fill, WG-exclusive, LDS atomics only -----
__global__ __launch_bounds__(256) void k_csr(const int* __restrict__ bktd,
    const int* __restrict__ bcd, int* __restrict__ cnt, int* __restrict__ ebuf,
    int N, int cap2) {
  __shared__ int lcnt[256];
  int fb = blockIdx.x;
  int tid = threadIdx.x;
  lcnt[tid] = 0;
  __syncthreads();
  int m = bcd[fb]; m = m < cap2 ? m : cap2;
  const int* rec = bktd + (size_t)fb * cap2;
  for (int i0 = tid * 4; i0 < m; i0 += 1024) {
    if (i0 + 4 <= m) {
      int4 r = *(const int4*)(rec + i0);
      int dl, s, p;
      dl = (unsigned)r.x >> 24; s = r.x & 0xFFFFFF;
      p = atomicAdd(&lcnt[dl], 1);
      if (p < MAXD) ebuf[((size_t)(fb << FBSH) + dl) * MAXD + p] = s;
      dl = (unsigned)r.y >> 24; s = r.y & 0xFFFFFF;
      p = atomicAdd(&lcnt[dl], 1);
      if (p < MAXD) ebuf[((size_t)(fb << FBSH) + dl) * MAXD + p] = s;
      dl = (unsigned)r.z >> 24; s = r.z & 0xFFFFFF;
      p = atomicAdd(&lcnt[dl], 1);
      if (p < MAXD) ebuf[((size_t)(fb << FBSH) + dl) * MAXD + p] = s;
      dl = (unsigned)r.w >> 24; s = r.w & 0xFFFFFF;
      p = atomicAdd(&lcnt[dl], 1);
      if (p < MAXD) ebuf[((size_t)(fb << FBSH) + dl) * MAXD + p] = s;
    } else {
      for (int k = i0; k < m; k++) {
        int r = rec[k];
        int dl = (unsigned)r >> 24; int s = r & 0xFFFFFF;
        int p = atomicAdd(&lcnt[dl], 1);
        if (p < MAXD) ebuf[((size_t)(fb << FBSH) + dl) * MAXD + p] = s;
      }
    }
  }
  __syncthreads();
  int node = (fb << FBSH) + tid;
  if (node < N) cnt[node] = lcnt[tid];   // true in-degree; spmm clamps at MAXD
}

// ---- phase C2: per-bucket out-degree histogram -------------------------
__global__ __launch_bounds__(256) void k_deg(const unsigned char* __restrict__ srec,
    const int* __restrict__ bcs, int* __restrict__ degout, int N, int cap2) {
  __shared__ int lh[256];
  int fb = blockIdx.x;
  int tid = threadIdx.x;
  lh[tid] = 0;
  __syncthreads();
  int m = bcs[fb]; m = m < cap2 ? m : cap2;
  const unsigned char* rec = srec + (size_t)fb * cap2;
  for (int i0 = tid * 4; i0 < m; i0 += 1024) {
    if (i0 + 4 <= m) {
      uchar4 r = *(const uchar4*)(rec + i0);
      atomicAdd(&lh[r.x], 1); atomicAdd(&lh[r.y], 1);
      atomicAdd(&lh[r.z], 1); atomicAdd(&lh[r.w], 1);
    } else {
      for (int k = i0; k < m; k++) atomicAdd(&lh[rec[k]], 1);
    }
  }
  __syncthreads();
  int node = (fb << FBSH) + tid;
  if (node < N) degout[node] = lh[tid];
}

__global__ __launch_bounds__(256) void k_scale(const int* __restrict__ degout,
    const int* __restrict__ cnt, float* __restrict__ sout,
    float* __restrict__ sin_, int N) {
  int i = blockIdx.x * 256 + threadIdx.x;
  if (i >= N) return;
  int dO = degout[i]; if (dO < 1) dO = 1;
  int dI = cnt[i];    if (dI < 1) dI = 1;
  sout[i] = rsqrtf((float)dO);
  sin_[i] = rsqrtf((float)dI);
}

// ---- fp32 -> bf16 row-major convert (features) ------------------------
__global__ __launch_bounds__(256) void k_cvt(const float* __restrict__ in,
    unsigned short* __restrict__ out, int n) {
  int i = (blockIdx.x * 256 + threadIdx.x) * 4;
  if (i >= n) return;
  float4 f = *(const float4*)(in + i);
  unsigned lo = (unsigned)f2bf(f.x) | ((unsigned)f2bf(f.y) << 16);
  unsigned hi = (unsigned)f2bf(f.z) | ((unsigned)f2bf(f.w) << 16);
  uint2 o; o.x = lo; o.y = hi;
  *(uint2*)(out + i) = o;
}

// ---- repack W[K][OC] fp32 -> bf16 B-fragment layout -------------------
template <int K, int OC>
__global__ __launch_bounds__(256) void k_wrepack(const float* __restrict__ W,
    short* __restrict__ Wp) {
  constexpr int KC = K / 32;
  constexpr int TOT = (OC / 16) * KC * 64;
  int t = blockIdx.x * 256 + threadIdx.x;
  if (t >= TOT) return;
  int lane = t & 63;
  int kc = (t >> 6) % KC;
  int nt = t / (KC * 64);
  int n = nt * 16 + (lane & 15);
  int k0 = kc * 32 + ((lane >> 4) * 8);
  short8 v;
  #pragma unroll
  for (int j = 0; j < 8; j++) v[j] = (short)f2bf(W[(size_t)(k0 + j) * OC + n]);
  *(short8*)(Wp + (size_t)t * 8) = v;
}

// ---- MFMA GEMM: C[N,OC] = A[N,K](bf16) @ Wp(frag bf16) (+bias, relu) --
template <int K, int OC, bool RELU, bool BIAS, bool OUTBF16>
__global__ __launch_bounds__(256) void k_gemm_mfma(
    const unsigned short* __restrict__ A, const short* __restrict__ Wp,
    const float* __restrict__ bias, void* __restrict__ Cout, int N) {
  constexpr int KC = K / 32;
  constexpr int NT = OC / 16;
  int lane = threadIdx.x & 63;
  int wv = threadIdx.x >> 6;
  int m0 = (blockIdx.x * 4 + wv) * 16;
  if (m0 >= N) return;
  int mrow = m0 + (lane & 15);
  if (mrow >= N) mrow = N - 1;          // clamp loads; stores predicated
  int q = lane >> 4;
  short8 av[KC];
  #pragma unroll
  for (int kc = 0; kc < KC; kc++)
    av[kc] = *(const short8*)(A + (size_t)mrow * K + kc * 32 + q * 8);
  int col0 = lane & 15;
  int rbase = m0 + q * 4;               // C/D: col=lane&15, row=(lane>>4)*4+r
  #pragma unroll
  for (int nt = 0; nt < NT; nt++) {
    f32x4 acc = {0.f, 0.f, 0.f, 0.f};
    #pragma unroll
    for (int kc = 0; kc < KC; kc++) {
      short8 bv = *(const short8*)(Wp + ((size_t)(nt * KC + kc) * 64 + lane) * 8);
      acc = __builtin_amdgcn_mfma_f32_16x16x32_bf16(av[kc], bv, acc, 0, 0, 0);
    }
    int col = nt * 16 + col0;
    float bb = BIAS ? bias[col] : 0.f;
    #pragma unroll
    for (int r = 0; r < 4; r++) {
      int row = rbase + r;
      if (row < N) {
        float v = acc[r] + bb;
        if (RELU) v = fmaxf(v, 0.f);
        if (OUTBF16) ((unsigned short*)Cout)[(size_t)row * OC + col] = f2bf(v);
        else         ((float*)Cout)[(size_t)row * OC + col] = v;
      }
    }
  }
}

// ---- SpMM (pull) dim=128 bf16: out[v] = s_in[v]*sum s_out[u]*x[u] -----
__global__ __launch_bounds__(256) void k_spmm128b(const unsigned short* __restrict__ x,
    const int* __restrict__ ebuf, const int* __restrict__ cnt,
    const float* __restrict__ sout, const float* __restrict__ sin_,
    unsigned short* __restrict__ out, int N) {
  int lane = threadIdx.x & 63;
  int v = blockIdx.x * 4 + (threadIdx.x >> 6);
  if (v >= N) return;
  v = __builtin_amdgcn_readfirstlane(v);
  int c = cnt[v]; c = c < MAXD ? c : MAXD;
  const int* el = ebuf + (size_t)v * MAXD;
  int u_l = 0; float w_l = 0.f;
  if (lane < c) { u_l = el[lane]; w_l = sout[u_l]; }
  float ax = 0.f, ay = 0.f;
  int i = 0;
  for (; i + 4 <= c; i += 4) {
    #pragma unroll
    for (int j = 0; j < 4; j++) {
      int u = __shfl(u_l, i + j);
      float w = __shfl(w_l, i + j);
      unsigned p = *(const unsigned*)(x + (size_t)u * 128 + lane * 2);
      float lo = __builtin_bit_cast(float, p << 16);
      float hi = __builtin_bit_cast(float, p & 0xFFFF0000u);
      ax = fmaf(w, lo, ax); ay = fmaf(w, hi, ay);
    }
  }
  for (; i < c; i++) {
    int u = __shfl(u_l, i);
    float w = __shfl(w_l, i);
    unsigned p = *(const unsigned*)(x + (size_t)u * 128 + lane * 2);
    float lo = __builtin_bit_cast(float, p << 16);
    float hi = __builtin_bit_cast(float, p & 0xFFFF0000u);
    ax = fmaf(w, lo, ax); ay = fmaf(w, hi, ay);
  }
  float sv = sin_[v];
  unsigned o = (unsigned)f2bf(sv * ax) | ((unsigned)f2bf(sv * ay) << 16);
  *(unsigned*)(out + (size_t)v * 128 + lane * 2) = o;
}

// ---- SpMM dim=128 bf16 + epilogue: +b2, split, z(bf16) ----------------
__global__ __launch_bounds__(256) void k_spmm2b(const unsigned short* __restrict__ hw,
    const int* __restrict__ ebuf, const int* __restrict__ cnt,
    const float* __restrict__ sout, const float* __restrict__ sin_,
    const float* __restrict__ b2, const float* __restrict__ eps,
    float* __restrict__ mean_out, float* __restrict__ logvar_out,
    unsigned short* __restrict__ z, int N) {
  int lane = threadIdx.x & 63;
  int v = blockIdx.x * 4 + (threadIdx.x >> 6);
  if (v >= N) return;
  v = __builtin_amdgcn_readfirstlane(v);
  int c = cnt[v]; c = c < MAXD ? c : MAXD;
  const int* el = ebuf + (size_t)v * MAXD;
  int u_l = 0; float w_l = 0.f;
  if (lane < c) { u_l = el[lane]; w_l = sout[u_l]; }
  float ax = 0.f, ay = 0.f;
  int i = 0;
  for (; i + 4 <= c; i += 4) {
    #pragma unroll
    for (int j = 0; j < 4; j++) {
      int u = __shfl(u_l, i + j);
      float w = __shfl(w_l, i + j);
      unsigned p = *(const unsigned*)(hw + (size_t)u * 128 + lane * 2);
      float lo = __builtin_bit_cast(float, p << 16);
      float hi = __builtin_bit_cast(float, p & 0xFFFF0000u);
      ax = fmaf(w, lo, ax); ay = fmaf(w, hi, ay);
    }
  }
  for (; i < c; i++) {
    int u = __shfl(u_l, i);
    float w = __shfl(w_l, i);
    unsigned p = *(const unsigned*)(hw + (size_t)u * 128 + lane * 2);
    float lo = __builtin_bit_cast(float, p << 16);
    float hi = __builtin_bit_cast(float, p & 0xFFFF0000u);
    ax = fmaf(w, lo, ax); ay = fmaf(w, hi, ay);
  }
  float sv = sin_[v];
  float2 bb = ((const float2*)b2)[lane];
  float mx = fmaf(sv, ax, bb.x);
  float my = fmaf(sv, ay, bb.y);
  // lanes 0..31: mean cols (2l,2l+1); lanes 32..63: logvar cols
  if (lane < 32) ((float2*)mean_out)[(size_t)v * 32 + lane] = make_float2(mx, my);
  else           ((float2*)logvar_out)[(size_t)v * 32 + (lane - 32)] = make_float2(mx, my);
  float lx = __shfl(mx, (lane & 31) + 32);
  float ly = __shfl(my, (lane & 31) + 32);
  if (lane < 32) {
    float2 e2 = ((const float2*)eps)[(size_t)v * 32 + lane];
    float zx = fmaf(e2.x, expf(0.5f * lx), mx);
    float zy = fmaf(e2.y, expf(0.5f * ly), my);
    unsigned o = (unsigned)f2bf(zx) | ((unsigned)f2bf(zy) << 16);
    *(unsigned*)(z + (size_t)v * 64 + lane * 2) = o;
  }
}

// ---- SpMM dim=64 bf16: aggz[v] = s_in[v]*sum s_out[u]*z[u] ------------
__global__ __launch_bounds__(256) void k_spmm64b(const unsigned short* __restrict__ z,
    const int* __restrict__ ebuf, const int* __restrict__ cnt,
    const float* __restrict__ sout, const float* __restrict__ sin_,
    unsigned short* __restrict__ aggz, int N) {
  int lane = threadIdx.x & 63;
  int v = blockIdx.x * 4 + (threadIdx.x >> 6);
  if (v >= N) return;
  v = __builtin_amdgcn_readfirstlane(v);
  int c = cnt[v]; c = c < MAXD ? c : MAXD;
  const int* el = ebuf + (size_t)v * MAXD;
  int u_l = 0; float w_l = 0.f;
  if (lane < c) { u_l = el[lane]; w_l = sout[u_l]; }
  float a = 0.f;
  int i = 0;
  for (; i + 8 <= c; i += 8) {
    #pragma unroll
    for (int j = 0; j < 8; j++) {
      int u = __shfl(u_l, i + j);
      float w = __shfl(w_l, i + j);
      a = fmaf(w, bf2f(z[(size_t)u * 64 + lane]), a);
    }
  }
  for (; i < c; i++) {
    int u = __shfl(u_l, i);
    float w = __shfl(w_l, i);
    a = fmaf(w, bf2f(z[(size_t)u * 64 + lane]), a);
  }
  aggz[(size_t)v * 64 + lane] = f2bf(sin_[v] * a);
}

extern "C" void kernel_launch(void* const* d_in, const int* in_sizes, int n_in,
                              void* d_out, int out_size, void* d_ws, size_t ws_size,
                              hipStream_t stream) {
  const float* features = (const float*)d_in[0];
  const int*   src      = (const int*)d_in[1];
  const int*   dst      = (const int*)d_in[2];
  const float* eps      = (const float*)d_in[3];
  const float* W1       = (const float*)d_in[4];
  const float* b1       = (const float*)d_in[5];
  const float* W2       = (const float*)d_in[6];
  const float* b2       = (const float*)d_in[7];
  const float* W3       = (const float*)d_in[8];
  const float* b3       = (const float*)d_in[9];
  const int E = in_sizes[1];
  const int N = in_sizes[3] / 64;   // eps is N x 64
  float* out = (float*)d_out;

  const int NFB = (N + 255) >> FBSH;                  // fine buckets (256 nodes)
  const int cap2 = ((E / NFB) + 2048 + 255) & ~255;   // records per bucket region

  // workspace (~78 MB): two aliased N*256-byte feature regions
  char* ws = (char*)d_ws;
  int* degout = (int*)ws;            ws += (size_t)N * 4;
  int* cnt    = (int*)ws;            ws += (size_t)N * 4;
  int* bcd    = (int*)ws;            ws += (size_t)NFB * 4;  // dst-bucket counts
  int* bcs    = (int*)ws;            ws += (size_t)NFB * 4;  // src-bucket counts
  int* ebuf   = (int*)ws;            ws += (size_t)N * MAXD * 4;
  float* sout = (float*)ws;          ws += (size_t)N * 4;
  float* sin_ = (float*)ws;          ws += (size_t)N * 4;
  short* W1p  = (short*)ws;          ws += 128 * 256 * 2;
  short* W2p  = (short*)ws;          ws += 256 * 128 * 2;
  short* W3p  = (short*)ws;          ws += 64 * 128 * 2;
  char* R1    = ws;                  ws += (size_t)N * 256;  // xb -> hwb -> aggz
  char* R2    = ws;                  ws += (size_t)N * 256;  // bktd/srec -> agg1 -> z

  unsigned short* xb    = (unsigned short*)R1;  // N x 128 bf16
  unsigned short* hwb   = (unsigned short*)R1;  // N x 128 bf16 (xb dead)
  unsigned short* aggzb = (unsigned short*)R1;  // N x 64  bf16 (hwb dead)
  unsigned short* agg1b = (unsigned short*)R2;  // N x 128 bf16
  unsigned short* zb    = (unsigned short*)R2;  // N x 64  bf16 (agg1 dead)
  // bucket records (~12MB) alias R2: dead before agg1b is written
  int* bktd = (int*)R2;                                     // NFB*cap2 4B records
  unsigned char* srec = (unsigned char*)(R2 + (size_t)NFB * cap2 * 4);

  // h (N x 256 bf16 = 51.2MB) lives in out[0..128N) floats; dead before recon
  unsigned short* h     = (unsigned short*)out;
  float* recon          = out;
  float* mean_out       = out + (size_t)N * 128;
  float* logvar_out     = out + (size_t)N * 192;

  // zero degout + cnt + bcd + bcs (contiguous)
  hipMemsetAsync(degout, 0, (size_t)N * 8 + (size_t)NFB * 8, stream);

  const size_t shA = (size_t)4 * NFB * 4;
  k_bucket2<<<(E + 256 * EPT - 1) / (256 * EPT), 256, shA, stream>>>(
      src, dst, bcd, bcs, bktd, srec, E, NFB, cap2);
  k_csr<<<NFB, 256, 0, stream>>>(bktd, bcd, cnt, ebuf, N, cap2);
  k_deg<<<NFB, 256, 0, stream>>>(srec, bcs, degout, N, cap2);
  k_scale<<<(N + 255) / 256, 256, 0, stream>>>(degout, cnt, sout, sin_, N);
  k_cvt<<<((N * 128 / 4) + 255) / 256, 256, 0, stream>>>(features, xb, N * 128);
  k_wrepack<128, 256><<<16, 256, 0, stream>>>(W1, W1p);
  k_wrepack<256, 128><<<16, 256, 0, stream>>>(W2, W2p);
  k_wrepack<64, 128><<<4, 256, 0, stream>>>(W3, W3p);

  // gconv1: SpMM(xb) -> agg1b; MFMA GEMM 128->256 +b1, relu -> h (bf16)
  k_spmm128b<<<(N + 3) / 4, 256, 0, stream>>>(xb, ebuf, cnt, sout, sin_, agg1b, N);
  k_gemm_mfma<128, 256, true, true, true>
      <<<(N + 63) / 64, 256, 0, stream>>>(agg1b, W1p, b1, h, N);

  // gconv2: MFMA GEMM 256->128 (h @ W2 -> hwb), then SpMM +b2, split, z(bf16)
  k_gemm_mfma<256, 128, false, false, true>
      <<<(N + 63) / 64, 256, 0, stream>>>(h, W2p, nullptr, hwb, N);
  k_spmm2b<<<(N + 3) / 4, 256, 0, stream>>>(hwb, ebuf, cnt, sout, sin_, b2, eps,
                                            mean_out, logvar_out, zb, N);

  // gconv3: SpMM(zb) -> aggzb (bf16); MFMA GEMM 64->128 +b3 -> recon
  k_spmm64b<<<(N + 3) / 4, 256, 0, stream>>>(zb, ebuf, cnt, sout, sin_, aggzb, N);
  k_gemm_mfma<64, 128, false, true, false>
      <<<(N + 63) / 64, 256, 0, stream>>>(aggzb, W3p, b3, recon, N);
}

// Round 4
// 526.592 us; speedup vs baseline: 1.1615x; 1.0278x over previous
//
#include <hip/hip_runtime.h>
#include <math.h>

// Graph VAE forward, bf16 edition.
//   SpMM at the narrow dim (gconv2 does GEMM first), pull-style padded CSR.
//   This round: weight-free vectorized SpMM.
//     - sout folded into rows (xb scaled in cvt, h scaled in gemm1 epilogue,
//       zb scaled in spmm2 epilogue) -> SpMM is a pure row-sum.
//     - dwordx4 gathers: 16 lanes cover a 256B row; 4 quarter-waves process
//       4 edges per load instr (8/iter unrolled); shfl_xor reduce at end.
//     - k_scale/degout deleted (rsqrt fused into k_csr/k_deg), memset 3KB.
//   CSR build (unchanged): LDS-bucketed two-phase, no per-edge global atomics.

#define MAXD 64   // padded per-node in-edge capacity; deg ~ Poisson(16)
#define FBSH 8    // 256 nodes per fine bucket (== blockDim of k_csr/k_deg)
#define EPT  16   // edges per thread in k_bucket2 (4096 per WG)

typedef short short8 __attribute__((ext_vector_type(8)));
typedef float f32x4 __attribute__((ext_vector_type(4)));

__device__ __forceinline__ unsigned short f2bf(float f) {
  union { float f; unsigned u; } c; c.f = f;
  unsigned r = c.u + 0x7FFF + ((c.u >> 16) & 1);   // RNE
  return (unsigned short)(r >> 16);
}
__device__ __forceinline__ float bf2f(unsigned short b) {
  return __builtin_bit_cast(float, (unsigned)b << 16);
}

// ---- phase A: two-level bucket, all per-edge counting in LDS -----------
__global__ __launch_bounds__(256) void k_bucket2(const int* __restrict__ src,
    const int* __restrict__ dst, int* __restrict__ bcd, int* __restrict__ bcs,
    int* __restrict__ bktd, unsigned char* __restrict__ srec,
    int E, int NFB, int cap2) {
  extern __shared__ int sh[];            // 4*NFB ints
  int* lcd = sh;                         // dst-bucket counts
  int* lbd = sh + NFB;                   // dst-bucket running offsets
  int* lcs = sh + 2 * NFB;               // src-bucket counts
  int* lbs = sh + 3 * NFB;               // src-bucket running offsets
  int tid = threadIdx.x;
  for (int i = tid; i < 4 * NFB; i += 256) sh[i] = 0;
  __syncthreads();
  int e0 = blockIdx.x * (256 * EPT);
  // pass 1: count per fine bucket (LDS atomics only)
  #pragma unroll 4
  for (int j = 0; j < EPT; j++) {
    int e = e0 + j * 256 + tid;
    if (e < E) {
      int d = dst[e]; atomicAdd(&lcd[d >> FBSH], 1);
      int s = src[e]; atomicAdd(&lcs[s >> FBSH], 1);
    }
  }
  __syncthreads();
  // reserve global chunks: one atomic per (WG, touched bucket)
  for (int fb = tid; fb < NFB; fb += 256) {
    int c = lcd[fb];
    if (c) lbd[fb] = atomicAdd(&bcd[fb], c);
    int cs = lcs[fb];
    if (cs) lbs[fb] = atomicAdd(&bcs[fb], cs);
  }
  __syncthreads();
  // pass 2: re-read edges (L1/L2 hot), place records
  #pragma unroll 4
  for (int j = 0; j < EPT; j++) {
    int e = e0 + j * 256 + tid;
    if (e < E) {
      int d = dst[e]; int s = src[e];
      int fbd = d >> FBSH;
      int od = atomicAdd(&lbd[fbd], 1);
      if (od < cap2) bktd[(size_t)fbd * cap2 + od] = ((d & 255) << 24) | s;
      int fbs = s >> FBSH;
      int os = atomicAdd(&lbs[fbs], 1);
      if (os < cap2) srec[(size_t)fbs * cap2 + os] = (unsigned char)(s & 255);
    }
  }
}

// ---- phase C1: per-bucket CSR fill + sin_ = rsqrt(in-degree) -----------
__global__ __launch_bounds__(256) void k_csr(const int* __restrict__ bktd,
    const int* __restrict__ bcd, int* __restrict__ cnt, float* __restrict__ sin_,
    int* __restrict__ ebuf, int N, int cap2) {
  __shared__ int lcnt[256];
  int fb = blockIdx.x;
  int tid = threadIdx.x;
  lcnt[tid] = 0;
  __syncthreads();
  int m = bcd[fb]; m = m < cap2 ? m : cap2;
  const int* rec = bktd + (size_t)fb * cap2;
  for (int i0 = tid * 4; i0 < m; i0 += 1024) {
    if (i0 + 4 <= m) {
      int4 r = *(const int4*)(rec + i0);
      int dl, s, p;
      dl = (unsigned)r.x >> 24; s = r.x & 0xFFFFFF;
      p = atomicAdd(&lcnt[dl], 1);
      if (p < MAXD) ebuf[((size_t)(fb << FBSH) + dl) * MAXD + p] = s;
      dl = (unsigned)r.y >> 24; s = r.y & 0xFFFFFF;
      p = atomicAdd(&lcnt[dl], 1);
      if (p < MAXD) ebuf[((size_t)(fb << FBSH) + dl) * MAXD + p] = s;
      dl = (unsigned)r.z >> 24; s = r.z & 0xFFFFFF;
      p = atomicAdd(&lcnt[dl], 1);
      if (p < MAXD) ebuf[((size_t)(fb << FBSH) + dl) * MAXD + p] = s;
      dl = (unsigned)r.w >> 24; s = r.w & 0xFFFFFF;
      p = atomicAdd(&lcnt[dl], 1);
      if (p < MAXD) ebuf[((size_t)(fb << FBSH) + dl) * MAXD + p] = s;
    } else {
      for (int k = i0; k < m; k++) {
        int r = rec[k];
        int dl = (unsigned)r >> 24; int s = r & 0xFFFFFF;
        int p = atomicAdd(&lcnt[dl], 1);
        if (p < MAXD) ebuf[((size_t)(fb << FBSH) + dl) * MAXD + p] = s;
      }
    }
  }
  __syncthreads();
  int node = (fb << FBSH) + tid;
  if (node < N) {
    int c = lcnt[tid];
    cnt[node] = c;                       // true in-degree; spmm clamps at MAXD
    sin_[node] = rsqrtf((float)(c < 1 ? 1 : c));
  }
}

// ---- phase C2: out-degree histogram -> sout = rsqrt(out-degree) --------
__global__ __launch_bounds__(256) void k_deg(const unsigned char* __restrict__ srec,
    const int* __restrict__ bcs, float* __restrict__ sout, int N, int cap2) {
  __shared__ int lh[256];
  int fb = blockIdx.x;
  int tid = threadIdx.x;
  lh[tid] = 0;
  __syncthreads();
  int m = bcs[fb]; m = m < cap2 ? m : cap2;
  const unsigned char* rec = srec + (size_t)fb * cap2;
  for (int i0 = tid * 4; i0 < m; i0 += 1024) {
    if (i0 + 4 <= m) {
      uchar4 r = *(const uchar4*)(rec + i0);
      atomicAdd(&lh[r.x], 1); atomicAdd(&lh[r.y], 1);
      atomicAdd(&lh[r.z], 1); atomicAdd(&lh[r.w], 1);
    } else {
      for (int k = i0; k < m; k++) atomicAdd(&lh[rec[k]], 1);
    }
  }
  __syncthreads();
  int node = (fb << FBSH) + tid;
  if (node < N) {
    int d = lh[tid];
    sout[node] = rsqrtf((float)(d < 1 ? 1 : d));
  }
}

// ---- fp32 -> bf16 convert, row pre-scaled by sout[row] ----------------
__global__ __launch_bounds__(256) void k_cvt(const float* __restrict__ in,
    const float* __restrict__ sout, unsigned short* __restrict__ out, int n) {
  int i = (blockIdx.x * 256 + threadIdx.x) * 4;
  if (i >= n) return;
  float s = sout[i >> 7];                // D=128; 4 elems never cross a row
  float4 f = *(const float4*)(in + i);
  unsigned lo = (unsigned)f2bf(s * f.x) | ((unsigned)f2bf(s * f.y) << 16);
  unsigned hi = (unsigned)f2bf(s * f.z) | ((unsigned)f2bf(s * f.w) << 16);
  uint2 o; o.x = lo; o.y = hi;
  *(uint2*)(out + i) = o;
}

// ---- repack W[K][OC] fp32 -> bf16 B-fragment layout -------------------
template <int K, int OC>
__global__ __launch_bounds__(256) void k_wrepack(const float* __restrict__ W,
    short* __restrict__ Wp) {
  constexpr int KC = K / 32;
  constexpr int TOT = (OC / 16) * KC * 64;
  int t = blockIdx.x * 256 + threadIdx.x;
  if (t >= TOT) return;
  int lane = t & 63;
  int kc = (t >> 6) % KC;
  int nt = t / (KC * 64);
  int n = nt * 16 + (lane & 15);
  int k0 = kc * 32 + ((lane >> 4) * 8);
  short8 v;
  #pragma unroll
  for (int j = 0; j < 8; j++) v[j] = (short)f2bf(W[(size_t)(k0 + j) * OC + n]);
  *(short8*)(Wp + (size_t)t * 8) = v;
}

// ---- MFMA GEMM: C[N,OC] = A[N,K](bf16) @ Wp (+bias, relu, row-scale) --
template <int K, int OC, bool RELU, bool BIAS, bool OUTBF16, bool SOUT>
__global__ __launch_bounds__(256) void k_gemm_mfma(
    const unsigned short* __restrict__ A, const short* __restrict__ Wp,
    const float* __restrict__ bias, const float* __restrict__ srow,
    void* __restrict__ Cout, int N) {
  constexpr int KC = K / 32;
  constexpr int NT = OC / 16;
  int lane = threadIdx.x & 63;
  int wv = threadIdx.x >> 6;
  int m0 = (blockIdx.x * 4 + wv) * 16;
  if (m0 >= N) return;
  int mrow = m0 + (lane & 15);
  if (mrow >= N) mrow = N - 1;          // clamp loads; stores predicated
  int q = lane >> 4;
  short8 av[KC];
  #pragma unroll
  for (int kc = 0; kc < KC; kc++)
    av[kc] = *(const short8*)(A + (size_t)mrow * K + kc * 32 + q * 8);
  int col0 = lane & 15;
  int rbase = m0 + q * 4;               // C/D: col=lane&15, row=(lane>>4)*4+r
  float sr[4];
  if (SOUT) {
    #pragma unroll
    for (int r = 0; r < 4; r++) {
      int row = rbase + r;
      sr[r] = (row < N) ? srow[row] : 1.f;
    }
  }
  #pragma unroll
  for (int nt = 0; nt < NT; nt++) {
    f32x4 acc = {0.f, 0.f, 0.f, 0.f};
    #pragma unroll
    for (int kc = 0; kc < KC; kc++) {
      short8 bv = *(const short8*)(Wp + ((size_t)(nt * KC + kc) * 64 + lane) * 8);
      acc = __builtin_amdgcn_mfma_f32_16x16x32_bf16(av[kc], bv, acc, 0, 0, 0);
    }
    int col = nt * 16 + col0;
    float bb = BIAS ? bias[col] : 0.f;
    #pragma unroll
    for (int r = 0; r < 4; r++) {
      int row = rbase + r;
      if (row < N) {
        float v = acc[r] + bb;
        if (RELU) v = fmaxf(v, 0.f);
        if (SOUT) v *= sr[r];
        if (OUTBF16) ((unsigned short*)Cout)[(size_t)row * OC + col] = f2bf(v);
        else         ((float*)Cout)[(size_t)row * OC + col] = v;
      }
    }
  }
}

// ---- SpMM 128-wide row-sum: out[v] = sin[v] * sum_{u in N(v)} x[u] ----
//   dwordx4 gathers: 16 lanes/row, 4 quarter-waves = 4 edges per load.
__global__ __launch_bounds__(256) void k_spmm128v(const unsigned short* __restrict__ x,
    const int* __restrict__ ebuf, const int* __restrict__ cnt,
    const float* __restrict__ sin_, unsigned short* __restrict__ out, int N) {
  int lane = threadIdx.x & 63;
  int v = blockIdx.x * 4 + (threadIdx.x >> 6);
  if (v >= N) return;
  v = __builtin_amdgcn_readfirstlane(v);
  int c = cnt[v]; c = c < MAXD ? c : MAXD;
  const int* el = ebuf + (size_t)v * MAXD;
  int u_l = (lane < c) ? el[lane] : 0;
  int q = lane >> 4;
  int fo = (lane & 15) * 8;             // ushort offset within row
  float a[8] = {0, 0, 0, 0, 0, 0, 0, 0};
  int i = 0;
  for (; i + 8 <= c; i += 8) {          // unmasked main: 8 edges, 2 loads
    int u0 = __shfl(u_l, i + q);
    int u1 = __shfl(u_l, i + 4 + q);
    uint4 p0 = *(const uint4*)(x + (size_t)u0 * 128 + fo);
    uint4 p1 = *(const uint4*)(x + (size_t)u1 * 128 + fo);
    a[0] += __builtin_bit_cast(float, p0.x << 16);
    a[1] += __builtin_bit_cast(float, p0.x & 0xFFFF0000u);
    a[2] += __builtin_bit_cast(float, p0.y << 16);
    a[3] += __builtin_bit_cast(float, p0.y & 0xFFFF0000u);
    a[4] += __builtin_bit_cast(float, p0.z << 16);
    a[5] += __builtin_bit_cast(float, p0.z & 0xFFFF0000u);
    a[6] += __builtin_bit_cast(float, p0.w << 16);
    a[7] += __builtin_bit_cast(float, p0.w & 0xFFFF0000u);
    a[0] += __builtin_bit_cast(float, p1.x << 16);
    a[1] += __builtin_bit_cast(float, p1.x & 0xFFFF0000u);
    a[2] += __builtin_bit_cast(float, p1.y << 16);
    a[3] += __builtin_bit_cast(float, p1.y & 0xFFFF0000u);
    a[4] += __builtin_bit_cast(float, p1.z << 16);
    a[5] += __builtin_bit_cast(float, p1.z & 0xFFFF0000u);
    a[6] += __builtin_bit_cast(float, p1.w << 16);
    a[7] += __builtin_bit_cast(float, p1.w & 0xFFFF0000u);
  }
  for (; i < c; i += 4) {               // masked tail: up to 4 edges
    int eidx = i + q;
    int u = __shfl(u_l, eidx);
    uint4 p = *(const uint4*)(x + (size_t)u * 128 + fo);
    if (eidx >= c) { p.x = 0; p.y = 0; p.z = 0; p.w = 0; }
    a[0] += __builtin_bit_cast(float, p.x << 16);
    a[1] += __builtin_bit_cast(float, p.x & 0xFFFF0000u);
    a[2] += __builtin_bit_cast(float, p.y << 16);
    a[3] += __builtin_bit_cast(float, p.y & 0xFFFF0000u);
    a[4] += __builtin_bit_cast(float, p.z << 16);
    a[5] += __builtin_bit_cast(float, p.z & 0xFFFF0000u);
    a[6] += __builtin_bit_cast(float, p.w << 16);
    a[7] += __builtin_bit_cast(float, p.w & 0xFFFF0000u);
  }
  #pragma unroll
  for (int j = 0; j < 8; j++) {
    a[j] += __shfl_xor(a[j], 16);
    a[j] += __shfl_xor(a[j], 32);
  }
  if (lane < 16) {
    float sv = sin_[v];
    uint4 o;
    o.x = (unsigned)f2bf(sv * a[0]) | ((unsigned)f2bf(sv * a[1]) << 16);
    o.y = (unsigned)f2bf(sv * a[2]) | ((unsigned)f2bf(sv * a[3]) << 16);
    o.z = (unsigned)f2bf(sv * a[4]) | ((unsigned)f2bf(sv * a[5]) << 16);
    o.w = (unsigned)f2bf(sv * a[6]) | ((unsigned)f2bf(sv * a[7]) << 16);
    *(uint4*)(out + (size_t)v * 128 + fo) = o;
  }
}

// ---- SpMM 128-wide row-sum + epilogue: +b2, split, z=sout*(eps*e^.5lv+m)
__global__ __launch_bounds__(256) void k_spmm2v(const unsigned short* __restrict__ hw,
    const int* __restrict__ ebuf, const int* __restrict__ cnt,
    const float* __restrict__ sout, const float* __restrict__ sin_,
    const float* __restrict__ b2, const float* __restrict__ eps,
    float* __restrict__ mean_out, float* __restrict__ logvar_out,
    unsigned short* __restrict__ z, int N) {
  int lane = threadIdx.x & 63;
  int v = blockIdx.x * 4 + (threadIdx.x >> 6);
  if (v >= N) return;
  v = __builtin_amdgcn_readfirstlane(v);
  int c = cnt[v]; c = c < MAXD ? c : MAXD;
  const int* el = ebuf + (size_t)v * MAXD;
  int u_l = (lane < c) ? el[lane] : 0;
  int q = lane >> 4;
  int fo = (lane & 15) * 8;
  float a[8] = {0, 0, 0, 0, 0, 0, 0, 0};
  int i = 0;
  for (; i + 8 <= c; i += 8) {
    int u0 = __shfl(u_l, i + q);
    int u1 = __shfl(u_l, i + 4 + q);
    uint4 p0 = *(const uint4*)(hw + (size_t)u0 * 128 + fo);
    uint4 p1 = *(const uint4*)(hw + (size_t)u1 * 128 + fo);
    a[0] += __builtin_bit_cast(float, p0.x << 16);
    a[1] += __builtin_bit_cast(float, p0.x & 0xFFFF0000u);
    a[2] += __builtin_bit_cast(float, p0.y << 16);
    a[3] += __builtin_bit_cast(float, p0.y & 0xFFFF0000u);
    a[4] += __builtin_bit_cast(float, p0.z << 16);
    a[5] += __builtin_bit_cast(float, p0.z & 0xFFFF0000u);
    a[6] += __builtin_bit_cast(float, p0.w << 16);
    a[7] += __builtin_bit_cast(float, p0.w & 0xFFFF0000u);
    a[0] += __builtin_bit_cast(float, p1.x << 16);
    a[1] += __builtin_bit_cast(float, p1.x & 0xFFFF0000u);
    a[2] += __builtin_bit_cast(float, p1.y << 16);
    a[3] += __builtin_bit_cast(float, p1.y & 0xFFFF0000u);
    a[4] += __builtin_bit_cast(float, p1.z << 16);
    a[5] += __builtin_bit_cast(float, p1.z & 0xFFFF0000u);
    a[6] += __builtin_bit_cast(float, p1.w << 16);
    a[7] += __builtin_bit_cast(float, p1.w & 0xFFFF0000u);
  }
  for (; i < c; i += 4) {
    int eidx = i + q;
    int u = __shfl(u_l, eidx);
    uint4 p = *(const uint4*)(hw + (size_t)u * 128 + fo);
    if (eidx >= c) { p.x = 0; p.y = 0; p.z = 0; p.w = 0; }
    a[0] += __builtin_bit_cast(float, p.x << 16);
    a[1] += __builtin_bit_cast(float, p.x & 0xFFFF0000u);
    a[2] += __builtin_bit_cast(float, p.y << 16);
    a[3] += __builtin_bit_cast(float, p.y & 0xFFFF0000u);
    a[4] += __builtin_bit_cast(float, p.z << 16);
    a[5] += __builtin_bit_cast(float, p.z & 0xFFFF0000u);
    a[6] += __builtin_bit_cast(float, p.w << 16);
    a[7] += __builtin_bit_cast(float, p.w & 0xFFFF0000u);
  }
  #pragma unroll
  for (int j = 0; j < 8; j++) {
    a[j] += __shfl_xor(a[j], 16);
    a[j] += __shfl_xor(a[j], 32);
  }
  // m[j] = sin[v]*a[j] + b2[fo+j]; features 0..63 = mean, 64..127 = logvar
  float sv = sin_[v];
  float4 blo = *(const float4*)(b2 + fo);
  float4 bhi = *(const float4*)(b2 + fo + 4);
  float m[8];
  m[0] = fmaf(sv, a[0], blo.x); m[1] = fmaf(sv, a[1], blo.y);
  m[2] = fmaf(sv, a[2], blo.z); m[3] = fmaf(sv, a[3], blo.w);
  m[4] = fmaf(sv, a[4], bhi.x); m[5] = fmaf(sv, a[5], bhi.y);
  m[6] = fmaf(sv, a[6], bhi.z); m[7] = fmaf(sv, a[7], bhi.w);
  float lv[8];
  #pragma unroll
  for (int j = 0; j < 8; j++) lv[j] = __shfl_xor(m[j], 8);  // pair k <-> k+8
  int k = lane & 15;
  if (lane < 16) {
    if (k < 8) {
      *(float4*)(mean_out + (size_t)v * 64 + k * 8) =
          make_float4(m[0], m[1], m[2], m[3]);
      *(float4*)(mean_out + (size_t)v * 64 + k * 8 + 4) =
          make_float4(m[4], m[5], m[6], m[7]);
      float so = sout[v];
      float4 e0 = *(const float4*)(eps + (size_t)v * 64 + k * 8);
      float4 e1 = *(const float4*)(eps + (size_t)v * 64 + k * 8 + 4);
      float z0 = so * fmaf(e0.x, expf(0.5f * lv[0]), m[0]);
      float z1 = so * fmaf(e0.y, expf(0.5f * lv[1]), m[1]);
      float z2 = so * fmaf(e0.z, expf(0.5f * lv[2]), m[2]);
      float z3 = so * fmaf(e0.w, expf(0.5f * lv[3]), m[3]);
      float z4 = so * fmaf(e1.x, expf(0.5f * lv[4]), m[4]);
      float z5 = so * fmaf(e1.y, expf(0.5f * lv[5]), m[5]);
      float z6 = so * fmaf(e1.z, expf(0.5f * lv[6]), m[6]);
      float z7 = so * fmaf(e1.w, expf(0.5f * lv[7]), m[7]);
      uint4 o;
      o.x = (unsigned)f2bf(z0) | ((unsigned)f2bf(z1) << 16);
      o.y = (unsigned)f2bf(z2) | ((unsigned)f2bf(z3) << 16);
      o.z = (unsigned)f2bf(z4) | ((unsigned)f2bf(z5) << 16);
      o.w = (unsigned)f2bf(z6) | ((unsigned)f2bf(z7) << 16);
      *(uint4*)(z + (size_t)v * 64 + k * 8) = o;
    } else {
      *(float4*)(logvar_out + (size_t)v * 64 + (k - 8) * 8) =
          make_float4(m[0], m[1], m[2], m[3]);
      *(float4*)(logvar_out + (size_t)v * 64 + (k - 8) * 8 + 4) =
          make_float4(m[4], m[5], m[6], m[7]);
    }
  }
}

// ---- SpMM 64-wide row-sum: 8 lanes/row, 8 octant-edges per load -------
__global__ __launch_bounds__(256) void k_spmm64v(const unsigned short* __restrict__ z,
    const int* __restrict__ ebuf, const int* __restrict__ cnt,
    const float* __restrict__ sin_, unsigned short* __restrict__ aggz, int N) {
  int lane = threadIdx.x & 63;
  int v = blockIdx.x * 4 + (threadIdx.x >> 6);
  if (v >= N) return;
  v = __builtin_amdgcn_readfirstlane(v);
  int c = cnt[v]; c = c < MAXD ? c : MAXD;
  const int* el = ebuf + (size_t)v * MAXD;
  int u_l = (lane < c) ? el[lane] : 0;
  int o8 = lane >> 3;
  int fo = (lane & 7) * 8;
  float a[8] = {0, 0, 0, 0, 0, 0, 0, 0};
  int i = 0;
  for (; i + 8 <= c; i += 8) {          // unmasked: 8 edges, 1 load
    int u = __shfl(u_l, i + o8);
    uint4 p = *(const uint4*)(z + (size_t)u * 64 + fo);
    a[0] += __builtin_bit_cast(float, p.x << 16);
    a[1] += __builtin_bit_cast(float, p.x & 0xFFFF0000u);
    a[2] += __builtin_bit_cast(float, p.y << 16);
    a[3] += __builtin_bit_cast(float, p.y & 0xFFFF0000u);
    a[4] += __builtin_bit_cast(float, p.z << 16);
    a[5] += __builtin_bit_cast(float, p.z & 0xFFFF0000u);
    a[6] += __builtin_bit_cast(float, p.w << 16);
    a[7] += __builtin_bit_cast(float, p.w & 0xFFFF0000u);
  }
  if (i < c) {                          // masked tail
    int eidx = i + o8;
    int u = __shfl(u_l, eidx);
    uint4 p = *(const uint4*)(z + (size_t)u * 64 + fo);
    if (eidx >= c) { p.x = 0; p.y = 0; p.z = 0; p.w = 0; }
    a[0] += __builtin_bit_cast(float, p.x << 16);
    a[1] += __builtin_bit_cast(float, p.x & 0xFFFF0000u);
    a[2] += __builtin_bit_cast(float, p.y << 16);
    a[3] += __builtin_bit_cast(float, p.y & 0xFFFF0000u);
    a[4] += __builtin_bit_cast(float, p.z << 16);
    a[5] += __builtin_bit_cast(float, p.z & 0xFFFF0000u);
    a[6] += __builtin_bit_cast(float, p.w << 16);
    a[7] += __builtin_bit_cast(float, p.w & 0xFFFF0000u);
  }
  #pragma unroll
  for (int j = 0; j < 8; j++) {
    a[j] += __shfl_xor(a[j], 8);
    a[j] += __shfl_xor(a[j], 16);
    a[j] += __shfl_xor(a[j], 32);
  }
  if (lane < 8) {
    float sv = sin_[v];
    uint4 o;
    o.x = (unsigned)f2bf(sv * a[0]) | ((unsigned)f2bf(sv * a[1]) << 16);
    o.y = (unsigned)f2bf(sv * a[2]) | ((unsigned)f2bf(sv * a[3]) << 16);
    o.z = (unsigned)f2bf(sv * a[4]) | ((unsigned)f2bf(sv * a[5]) << 16);
    o.w = (unsigned)f2bf(sv * a[6]) | ((unsigned)f2bf(sv * a[7]) << 16);
    *(uint4*)(aggz + (size_t)v * 64 + fo) = o;
  }
}

extern "C" void kernel_launch(void* const* d_in, const int* in_sizes, int n_in,
                              void* d_out, int out_size, void* d_ws, size_t ws_size,
                              hipStream_t stream) {
  const float* features = (const float*)d_in[0];
  const int*   src      = (const int*)d_in[1];
  const int*   dst      = (const int*)d_in[2];
  const float* eps      = (const float*)d_in[3];
  const float* W1       = (const float*)d_in[4];
  const float* b1       = (const float*)d_in[5];
  const float* W2       = (const float*)d_in[6];
  const float* b2       = (const float*)d_in[7];
  const float* W3       = (const float*)d_in[8];
  const float* b3       = (const float*)d_in[9];
  const int E = in_sizes[1];
  const int N = in_sizes[3] / 64;   // eps is N x 64
  float* out = (float*)d_out;

  const int NFB = (N + 255) >> FBSH;                  // fine buckets (256 nodes)
  const int cap2 = ((E / NFB) + 2048 + 255) & ~255;   // records per bucket region

  // workspace (~78 MB): two aliased N*256-byte feature regions
  char* ws = (char*)d_ws;
  int* cnt    = (int*)ws;            ws += (size_t)N * 4;
  int* bcd    = (int*)ws;            ws += (size_t)NFB * 4;  // dst-bucket counts
  int* bcs    = (int*)ws;            ws += (size_t)NFB * 4;  // src-bucket counts
  int* ebuf   = (int*)ws;            ws += (size_t)N * MAXD * 4;
  float* sout = (float*)ws;          ws += (size_t)N * 4;
  float* sin_ = (float*)ws;          ws += (size_t)N * 4;
  short* W1p  = (short*)ws;          ws += 128 * 256 * 2;
  short* W2p  = (short*)ws;          ws += 256 * 128 * 2;
  short* W3p  = (short*)ws;          ws += 64 * 128 * 2;
  char* R1    = ws;                  ws += (size_t)N * 256;  // xb -> hwb -> aggz
  char* R2    = ws;                  ws += (size_t)N * 256;  // bktd/srec -> agg1 -> z

  unsigned short* xb    = (unsigned short*)R1;  // N x 128 bf16 (sout-scaled)
  unsigned short* hwb   = (unsigned short*)R1;  // N x 128 bf16 (xb dead)
  unsigned short* aggzb = (unsigned short*)R1;  // N x 64  bf16 (hwb dead)
  unsigned short* agg1b = (unsigned short*)R2;  // N x 128 bf16
  unsigned short* zb    = (unsigned short*)R2;  // N x 64  bf16 (agg1 dead, sout-scaled)
  // bucket records (~12MB) alias R2: dead before agg1b is written
  int* bktd = (int*)R2;                                     // NFB*cap2 4B records
  unsigned char* srec = (unsigned char*)(R2 + (size_t)NFB * cap2 * 4);

  // h (N x 256 bf16 = 51.2MB) lives in out[0..128N) floats; dead before recon
  unsigned short* h     = (unsigned short*)out;
  float* recon          = out;
  float* mean_out       = out + (size_t)N * 128;
  float* logvar_out     = out + (size_t)N * 192;

  hipMemsetAsync(bcd, 0, (size_t)NFB * 8, stream);   // bucket counters only

  const size_t shA = (size_t)4 * NFB * 4;
  k_bucket2<<<(E + 256 * EPT - 1) / (256 * EPT), 256, shA, stream>>>(
      src, dst, bcd, bcs, bktd, srec, E, NFB, cap2);
  k_csr<<<NFB, 256, 0, stream>>>(bktd, bcd, cnt, sin_, ebuf, N, cap2);
  k_deg<<<NFB, 256, 0, stream>>>(srec, bcs, sout, N, cap2);
  k_cvt<<<((N * 128 / 4) + 255) / 256, 256, 0, stream>>>(features, sout, xb, N * 128);
  k_wrepack<128, 256><<<16, 256, 0, stream>>>(W1, W1p);
  k_wrepack<256, 128><<<16, 256, 0, stream>>>(W2, W2p);
  k_wrepack<64, 128><<<4, 256, 0, stream>>>(W3, W3p);

  // gconv1: row-sum SpMM(xb) -> agg1b; GEMM 128->256 +b1, relu, x sout -> h
  k_spmm128v<<<(N + 3) / 4, 256, 0, stream>>>(xb, ebuf, cnt, sin_, agg1b, N);
  k_gemm_mfma<128, 256, true, true, true, true>
      <<<(N + 63) / 64, 256, 0, stream>>>(agg1b, W1p, b1, sout, h, N);

  // gconv2: GEMM 256->128 (h @ W2 -> hwb), row-sum SpMM +b2, split, z(bf16)
  k_gemm_mfma<256, 128, false, false, true, false>
      <<<(N + 63) / 64, 256, 0, stream>>>(h, W2p, nullptr, nullptr, hwb, N);
  k_spmm2v<<<(N + 3) / 4, 256, 0, stream>>>(hwb, ebuf, cnt, sout, sin_, b2, eps,
                                            mean_out, logvar_out, zb, N);

  // gconv3: row-sum SpMM(zb) -> aggzb; GEMM 64->128 +b3 -> recon
  k_spmm64v<<<(N + 3) / 4, 256, 0, stream>>>(zb, ebuf, cnt, sin_, aggzb, N);
  k_gemm_mfma<64, 128, false, true, false, false>
      <<<(N + 63) / 64, 256, 0, stream>>>(aggzb, W3p, b3, nullptr, recon, N);
}

// Round 8
// 519.830 us; speedup vs baseline: 1.1766x; 1.0130x over previous
//
#include <hip/hip_runtime.h>
#include <math.h>

// Graph VAE forward, bf16 edition.
//   SpMM at the narrow dim (gconv2 does GEMM first), pull-style padded CSR.
//   Weight-free row-sum SpMM (sout folded into rows), dwordx4 gathers.
//   This round: deep-MLP SpMM (4 gather loads in flight per wave),
//     k_csr+k_deg merged, 3 wrepacks merged (launch-count 13 -> 10).
//   CSR build: LDS-bucketed two-phase, no per-edge global atomics.

#define MAXD 64   // padded per-node in-edge capacity; deg ~ Poisson(16)
#define FBSH 8    // 256 nodes per fine bucket (== blockDim of k_csrdeg)
#define EPT  16   // edges per thread in k_bucket2 (4096 per WG)

typedef short short8 __attribute__((ext_vector_type(8)));
typedef float f32x4 __attribute__((ext_vector_type(4)));

__device__ __forceinline__ unsigned short f2bf(float f) {
  union { float f; unsigned u; } c; c.f = f;
  unsigned r = c.u + 0x7FFF + ((c.u >> 16) & 1);   // RNE
  return (unsigned short)(r >> 16);
}
__device__ __forceinline__ float bf2f(unsigned short b) {
  return __builtin_bit_cast(float, (unsigned)b << 16);
}
// accumulate 8 bf16 (packed in uint4) into a[0..7]
__device__ __forceinline__ void acc8(float* a, uint4 p) {
  a[0] += __builtin_bit_cast(float, p.x << 16);
  a[1] += __builtin_bit_cast(float, p.x & 0xFFFF0000u);
  a[2] += __builtin_bit_cast(float, p.y << 16);
  a[3] += __builtin_bit_cast(float, p.y & 0xFFFF0000u);
  a[4] += __builtin_bit_cast(float, p.z << 16);
  a[5] += __builtin_bit_cast(float, p.z & 0xFFFF0000u);
  a[6] += __builtin_bit_cast(float, p.w << 16);
  a[7] += __builtin_bit_cast(float, p.w & 0xFFFF0000u);
}

// ---- phase A: two-level bucket, all per-edge counting in LDS -----------
__global__ __launch_bounds__(256) void k_bucket2(const int* __restrict__ src,
    const int* __restrict__ dst, int* __restrict__ bcd, int* __restrict__ bcs,
    int* __restrict__ bktd, unsigned char* __restrict__ srec,
    int E, int NFB, int cap2) {
  extern __shared__ int sh[];            // 4*NFB ints
  int* lcd = sh;                         // dst-bucket counts
  int* lbd = sh + NFB;                   // dst-bucket running offsets
  int* lcs = sh + 2 * NFB;               // src-bucket counts
  int* lbs = sh + 3 * NFB;               // src-bucket running offsets
  int tid = threadIdx.x;
  for (int i = tid; i < 4 * NFB; i += 256) sh[i] = 0;
  __syncthreads();
  int e0 = blockIdx.x * (256 * EPT);
  // pass 1: count per fine bucket (LDS atomics only)
  #pragma unroll 4
  for (int j = 0; j < EPT; j++) {
    int e = e0 + j * 256 + tid;
    if (e < E) {
      int d = dst[e]; atomicAdd(&lcd[d >> FBSH], 1);
      int s = src[e]; atomicAdd(&lcs[s >> FBSH], 1);
    }
  }
  __syncthreads();
  // reserve global chunks: one atomic per (WG, touched bucket)
  for (int fb = tid; fb < NFB; fb += 256) {
    int c = lcd[fb];
    if (c) lbd[fb] = atomicAdd(&bcd[fb], c);
    int cs = lcs[fb];
    if (cs) lbs[fb] = atomicAdd(&bcs[fb], cs);
  }
  __syncthreads();
  // pass 2: re-read edges (L1/L2 hot), place records
  #pragma unroll 4
  for (int j = 0; j < EPT; j++) {
    int e = e0 + j * 256 + tid;
    if (e < E) {
      int d = dst[e]; int s = src[e];
      int fbd = d >> FBSH;
      int od = atomicAdd(&lbd[fbd], 1);
      if (od < cap2) bktd[(size_t)fbd * cap2 + od] = ((d & 255) << 24) | s;
      int fbs = s >> FBSH;
      int os = atomicAdd(&lbs[fbs], 1);
      if (os < cap2) srec[(size_t)fbs * cap2 + os] = (unsigned char)(s & 255);
    }
  }
}

// ---- phase C: per-bucket CSR fill + in/out-degree scales ---------------
__global__ __launch_bounds__(256) void k_csrdeg(const int* __restrict__ bktd,
    const int* __restrict__ bcd, const unsigned char* __restrict__ srec,
    const int* __restrict__ bcs, int* __restrict__ cnt, float* __restrict__ sin_,
    float* __restrict__ sout, int* __restrict__ ebuf, int N, int cap2) {
  __shared__ int lcnt[256];
  __shared__ int lh[256];
  int fb = blockIdx.x;
  int tid = threadIdx.x;
  lcnt[tid] = 0;
  lh[tid] = 0;
  __syncthreads();
  // C1: CSR fill from dst-bucket records
  {
    int m = bcd[fb]; m = m < cap2 ? m : cap2;
    const int* rec = bktd + (size_t)fb * cap2;
    for (int i0 = tid * 4; i0 < m; i0 += 1024) {
      if (i0 + 4 <= m) {
        int4 r = *(const int4*)(rec + i0);
        int dl, s, p;
        dl = (unsigned)r.x >> 24; s = r.x & 0xFFFFFF;
        p = atomicAdd(&lcnt[dl], 1);
        if (p < MAXD) ebuf[((size_t)(fb << FBSH) + dl) * MAXD + p] = s;
        dl = (unsigned)r.y >> 24; s = r.y & 0xFFFFFF;
        p = atomicAdd(&lcnt[dl], 1);
        if (p < MAXD) ebuf[((size_t)(fb << FBSH) + dl) * MAXD + p] = s;
        dl = (unsigned)r.z >> 24; s = r.z & 0xFFFFFF;
        p = atomicAdd(&lcnt[dl], 1);
        if (p < MAXD) ebuf[((size_t)(fb << FBSH) + dl) * MAXD + p] = s;
        dl = (unsigned)r.w >> 24; s = r.w & 0xFFFFFF;
        p = atomicAdd(&lcnt[dl], 1);
        if (p < MAXD) ebuf[((size_t)(fb << FBSH) + dl) * MAXD + p] = s;
      } else {
        for (int k = i0; k < m; k++) {
          int r = rec[k];
          int dl = (unsigned)r >> 24; int s = r & 0xFFFFFF;
          int p = atomicAdd(&lcnt[dl], 1);
          if (p < MAXD) ebuf[((size_t)(fb << FBSH) + dl) * MAXD + p] = s;
        }
      }
    }
  }
  // C2: out-degree histogram from src-bucket records
  {
    int m = bcs[fb]; m = m < cap2 ? m : cap2;
    const unsigned char* rec = srec + (size_t)fb * cap2;
    for (int i0 = tid * 4; i0 < m; i0 += 1024) {
      if (i0 + 4 <= m) {
        uchar4 r = *(const uchar4*)(rec + i0);
        atomicAdd(&lh[r.x], 1); atomicAdd(&lh[r.y], 1);
        atomicAdd(&lh[r.z], 1); atomicAdd(&lh[r.w], 1);
      } else {
        for (int k = i0; k < m; k++) atomicAdd(&lh[rec[k]], 1);
      }
    }
  }
  __syncthreads();
  int node = (fb << FBSH) + tid;
  if (node < N) {
    int c = lcnt[tid];
    cnt[node] = c;                       // true in-degree; spmm clamps at MAXD
    sin_[node] = rsqrtf((float)(c < 1 ? 1 : c));
    int d = lh[tid];
    sout[node] = rsqrtf((float)(d < 1 ? 1 : d));
  }
}

// ---- fp32 -> bf16 convert, row pre-scaled by sout[row] ----------------
__global__ __launch_bounds__(256) void k_cvt(const float* __restrict__ in,
    const float* __restrict__ sout, unsigned short* __restrict__ out, int n) {
  int i = (blockIdx.x * 256 + threadIdx.x) * 4;
  if (i >= n) return;
  float s = sout[i >> 7];                // D=128; 4 elems never cross a row
  float4 f = *(const float4*)(in + i);
  unsigned lo = (unsigned)f2bf(s * f.x) | ((unsigned)f2bf(s * f.y) << 16);
  unsigned hi = (unsigned)f2bf(s * f.z) | ((unsigned)f2bf(s * f.w) << 16);
  uint2 o; o.x = lo; o.y = hi;
  *(uint2*)(out + i) = o;
}

// ---- repack W[K][OC] fp32 -> bf16 B-fragment layout (all 3 in one) ----
template <int K, int OC>
__device__ __forceinline__ void wrepack_body(const float* __restrict__ W,
    short* __restrict__ Wp, int t) {
  constexpr int KC = K / 32;
  int lane = t & 63;
  int kc = (t >> 6) % KC;
  int nt = t / (KC * 64);
  int n = nt * 16 + (lane & 15);
  int k0 = kc * 32 + ((lane >> 4) * 8);
  short8 v;
  #pragma unroll
  for (int j = 0; j < 8; j++) v[j] = (short)f2bf(W[(size_t)(k0 + j) * OC + n]);
  *(short8*)(Wp + (size_t)t * 8) = v;
}

__global__ __launch_bounds__(256) void k_wrepack_all(
    const float* __restrict__ W1, const float* __restrict__ W2,
    const float* __restrict__ W3, short* __restrict__ W1p,
    short* __restrict__ W2p, short* __restrict__ W3p) {
  int t = blockIdx.x * 256 + threadIdx.x;
  if (t < 4096) wrepack_body<128, 256>(W1, W1p, t);             // 16*4*64
  else if (t < 8192) wrepack_body<256, 128>(W2, W2p, t - 4096); // 8*8*64
  else if (t < 9216) wrepack_body<64, 128>(W3, W3p, t - 8192);  // 8*2*64
}

// ---- MFMA GEMM: C[N,OC] = A[N,K](bf16) @ Wp (+bias, relu, row-scale) --
template <int K, int OC, bool RELU, bool BIAS, bool OUTBF16, bool SOUT>
__global__ __launch_bounds__(256) void k_gemm_mfma(
    const unsigned short* __restrict__ A, const short* __restrict__ Wp,
    const float* __restrict__ bias, const float* __restrict__ srow,
    void* __restrict__ Cout, int N) {
  constexpr int KC = K / 32;
  constexpr int NT = OC / 16;
  int lane = threadIdx.x & 63;
  int wv = threadIdx.x >> 6;
  int m0 = (blockIdx.x * 4 + wv) * 16;
  if (m0 >= N) return;
  int mrow = m0 + (lane & 15);
  if (mrow >= N) mrow = N - 1;          // clamp loads; stores predicated
  int q = lane >> 4;
  short8 av[KC];
  #pragma unroll
  for (int kc = 0; kc < KC; kc++)
    av[kc] = *(const short8*)(A + (size_t)mrow * K + kc * 32 + q * 8);
  int col0 = lane & 15;
  int rbase = m0 + q * 4;               // C/D: col=lane&15, row=(lane>>4)*4+r
  float sr[4];
  if (SOUT) {
    #pragma unroll
    for (int r = 0; r < 4; r++) {
      int row = rbase + r;
      sr[r] = (row < N) ? srow[row] : 1.f;
    }
  }
  #pragma unroll
  for (int nt = 0; nt < NT; nt++) {
    f32x4 acc = {0.f, 0.f, 0.f, 0.f};
    #pragma unroll
    for (int kc = 0; kc < KC; kc++) {
      short8 bv = *(const short8*)(Wp + ((size_t)(nt * KC + kc) * 64 + lane) * 8);
      acc = __builtin_amdgcn_mfma_f32_16x16x32_bf16(av[kc], bv, acc, 0, 0, 0);
    }
    int col = nt * 16 + col0;
    float bb = BIAS ? bias[col] : 0.f;
    #pragma unroll
    for (int r = 0; r < 4; r++) {
      int row = rbase + r;
      if (row < N) {
        float v = acc[r] + bb;
        if (RELU) v = fmaxf(v, 0.f);
        if (SOUT) v *= sr[r];
        if (OUTBF16) ((unsigned short*)Cout)[(size_t)row * OC + col] = f2bf(v);
        else         ((float*)Cout)[(size_t)row * OC + col] = v;
      }
    }
  }
}

// ---- SpMM 128-wide row-sum, deep-MLP: 4 gather loads in flight --------
//   16 lanes/row, 4 quarter-waves; 16-edge chunks then 8 then masked 4.
__global__ __launch_bounds__(256) void k_spmm128v(const unsigned short* __restrict__ x,
    const int* __restrict__ ebuf, const int* __restrict__ cnt,
    const float* __restrict__ sin_, unsigned short* __restrict__ out, int N) {
  int lane = threadIdx.x & 63;
  int v = blockIdx.x * 4 + (threadIdx.x >> 6);
  if (v >= N) return;
  v = __builtin_amdgcn_readfirstlane(v);
  int c = cnt[v]; c = c < MAXD ? c : MAXD;
  const int* el = ebuf + (size_t)v * MAXD;
  int u_l = (lane < c) ? el[lane] : 0;
  int q = lane >> 4;
  int fo = (lane & 15) * 8;             // ushort offset within row
  float a[8] = {0, 0, 0, 0, 0, 0, 0, 0};
  int i = 0;
  for (; i + 16 <= c; i += 16) {        // 16 edges, 4 loads in flight
    int u0 = __shfl(u_l, i + q);
    int u1 = __shfl(u_l, i + 4 + q);
    int u2 = __shfl(u_l, i + 8 + q);
    int u3 = __shfl(u_l, i + 12 + q);
    uint4 p0 = *(const uint4*)(x + (size_t)u0 * 128 + fo);
    uint4 p1 = *(const uint4*)(x + (size_t)u1 * 128 + fo);
    uint4 p2 = *(const uint4*)(x + (size_t)u2 * 128 + fo);
    uint4 p3 = *(const uint4*)(x + (size_t)u3 * 128 + fo);
    acc8(a, p0); acc8(a, p1); acc8(a, p2); acc8(a, p3);
  }
  for (; i + 8 <= c; i += 8) {          // 8 edges, 2 loads
    int u0 = __shfl(u_l, i + q);
    int u1 = __shfl(u_l, i + 4 + q);
    uint4 p0 = *(const uint4*)(x + (size_t)u0 * 128 + fo);
    uint4 p1 = *(const uint4*)(x + (size_t)u1 * 128 + fo);
    acc8(a, p0); acc8(a, p1);
  }
  for (; i < c; i += 4) {               // masked tail: up to 4 edges
    int eidx = i + q;
    int u = __shfl(u_l, eidx);
    uint4 p = *(const uint4*)(x + (size_t)u * 128 + fo);
    if (eidx >= c) { p.x = 0; p.y = 0; p.z = 0; p.w = 0; }
    acc8(a, p);
  }
  #pragma unroll
  for (int j = 0; j < 8; j++) {
    a[j] += __shfl_xor(a[j], 16);
    a[j] += __shfl_xor(a[j], 32);
  }
  if (lane < 16) {
    float sv = sin_[v];
    uint4 o;
    o.x = (unsigned)f2bf(sv * a[0]) | ((unsigned)f2bf(sv * a[1]) << 16);
    o.y = (unsigned)f2bf(sv * a[2]) | ((unsigned)f2bf(sv * a[3]) << 16);
    o.z = (unsigned)f2bf(sv * a[4]) | ((unsigned)f2bf(sv * a[5]) << 16);
    o.w = (unsigned)f2bf(sv * a[6]) | ((unsigned)f2bf(sv * a[7]) << 16);
    *(uint4*)(out + (size_t)v * 128 + fo) = o;
  }
}

// ---- SpMM 128-wide row-sum + epilogue: +b2, split, z=sout*(eps*e^.5lv+m)
__global__ __launch_bounds__(256) void k_spmm2v(const unsigned short* __restrict__ hw,
    const int* __restrict__ ebuf, const int* __restrict__ cnt,
    const float* __restrict__ sout, const float* __restrict__ sin_,
    const float* __restrict__ b2, const float* __restrict__ eps,
    float* __restrict__ mean_out, float* __restrict__ logvar_out,
    unsigned short* __restrict__ z, int N) {
  int lane = threadIdx.x & 63;
  int v = blockIdx.x * 4 + (threadIdx.x >> 6);
  if (v >= N) return;
  v = __builtin_amdgcn_readfirstlane(v);
  int c = cnt[v]; c = c < MAXD ? c : MAXD;
  const int* el = ebuf + (size_t)v * MAXD;
  int u_l = (lane < c) ? el[lane] : 0;
  int q = lane >> 4;
  int fo = (lane & 15) * 8;
  float a[8] = {0, 0, 0, 0, 0, 0, 0, 0};
  int i = 0;
  for (; i + 16 <= c; i += 16) {
    int u0 = __shfl(u_l, i + q);
    int u1 = __shfl(u_l, i + 4 + q);
    int u2 = __shfl(u_l, i + 8 + q);
    int u3 = __shfl(u_l, i + 12 + q);
    uint4 p0 = *(const uint4*)(hw + (size_t)u0 * 128 + fo);
    uint4 p1 = *(const uint4*)(hw + (size_t)u1 * 128 + fo);
    uint4 p2 = *(const uint4*)(hw + (size_t)u2 * 128 + fo);
    uint4 p3 = *(const uint4*)(hw + (size_t)u3 * 128 + fo);
    acc8(a, p0); acc8(a, p1); acc8(a, p2); acc8(a, p3);
  }
  for (; i + 8 <= c; i += 8) {
    int u0 = __shfl(u_l, i + q);
    int u1 = __shfl(u_l, i + 4 + q);
    uint4 p0 = *(const uint4*)(hw + (size_t)u0 * 128 + fo);
    uint4 p1 = *(const uint4*)(hw + (size_t)u1 * 128 + fo);
    acc8(a, p0); acc8(a, p1);
  }
  for (; i < c; i += 4) {
    int eidx = i + q;
    int u = __shfl(u_l, eidx);
    uint4 p = *(const uint4*)(hw + (size_t)u * 128 + fo);
    if (eidx >= c) { p.x = 0; p.y = 0; p.z = 0; p.w = 0; }
    acc8(a, p);
  }
  #pragma unroll
  for (int j = 0; j < 8; j++) {
    a[j] += __shfl_xor(a[j], 16);
    a[j] += __shfl_xor(a[j], 32);
  }
  // m[j] = sin[v]*a[j] + b2[fo+j]; features 0..63 = mean, 64..127 = logvar
  float sv = sin_[v];
  float4 blo = *(const float4*)(b2 + fo);
  float4 bhi = *(const float4*)(b2 + fo + 4);
  float m[8];
  m[0] = fmaf(sv, a[0], blo.x); m[1] = fmaf(sv, a[1], blo.y);
  m[2] = fmaf(sv, a[2], blo.z); m[3] = fmaf(sv, a[3], blo.w);
  m[4] = fmaf(sv, a[4], bhi.x); m[5] = fmaf(sv, a[5], bhi.y);
  m[6] = fmaf(sv, a[6], bhi.z); m[7] = fmaf(sv, a[7], bhi.w);
  float lv[8];
  #pragma unroll
  for (int j = 0; j < 8; j++) lv[j] = __shfl_xor(m[j], 8);  // pair k <-> k+8
  int k = lane & 15;
  if (lane < 16) {
    if (k < 8) {
      *(float4*)(mean_out + (size_t)v * 64 + k * 8) =
          make_float4(m[0], m[1], m[2], m[3]);
      *(float4*)(mean_out + (size_t)v * 64 + k * 8 + 4) =
          make_float4(m[4], m[5], m[6], m[7]);
      float so = sout[v];
      float4 e0 = *(const float4*)(eps + (size_t)v * 64 + k * 8);
      float4 e1 = *(const float4*)(eps + (size_t)v * 64 + k * 8 + 4);
      float z0 = so * fmaf(e0.x, expf(0.5f * lv[0]), m[0]);
      float z1 = so * fmaf(e0.y, expf(0.5f * lv[1]), m[1]);
      float z2 = so * fmaf(e0.z, expf(0.5f * lv[2]), m[2]);
      float z3 = so * fmaf(e0.w, expf(0.5f * lv[3]), m[3]);
      float z4 = so * fmaf(e1.x, expf(0.5f * lv[4]), m[4]);
      float z5 = so * fmaf(e1.y, expf(0.5f * lv[5]), m[5]);
      float z6 = so * fmaf(e1.z, expf(0.5f * lv[6]), m[6]);
      float z7 = so * fmaf(e1.w, expf(0.5f * lv[7]), m[7]);
      uint4 o;
      o.x = (unsigned)f2bf(z0) | ((unsigned)f2bf(z1) << 16);
      o.y = (unsigned)f2bf(z2) | ((unsigned)f2bf(z3) << 16);
      o.z = (unsigned)f2bf(z4) | ((unsigned)f2bf(z5) << 16);
      o.w = (unsigned)f2bf(z6) | ((unsigned)f2bf(z7) << 16);
      *(uint4*)(z + (size_t)v * 64 + k * 8) = o;
    } else {
      *(float4*)(logvar_out + (size_t)v * 64 + (k - 8) * 8) =
          make_float4(m[0], m[1], m[2], m[3]);
      *(float4*)(logvar_out + (size_t)v * 64 + (k - 8) * 8 + 4) =
          make_float4(m[4], m[5], m[6], m[7]);
    }
  }
}

// ---- SpMM 64-wide row-sum, deep-MLP: 8 lanes/row, 8 edges per load ----
__global__ __launch_bounds__(256) void k_spmm64v(const unsigned short* __restrict__ z,
    const int* __restrict__ ebuf, const int* __restrict__ cnt,
    const float* __restrict__ sin_, unsigned short* __restrict__ aggz, int N) {
  int lane = threadIdx.x & 63;
  int v = blockIdx.x * 4 + (threadIdx.x >> 6);
  if (v >= N) return;
  v = __builtin_amdgcn_readfirstlane(v);
  int c = cnt[v]; c = c < MAXD ? c : MAXD;
  const int* el = ebuf + (size_t)v * MAXD;
  int u_l = (lane < c) ? el[lane] : 0;
  int o8 = lane >> 3;
  int fo = (lane & 7) * 8;
  float a[8] = {0, 0, 0, 0, 0, 0, 0, 0};
  int i = 0;
  for (; i + 32 <= c; i += 32) {        // 32 edges, 4 loads in flight
    int u0 = __shfl(u_l, i + o8);
    int u1 = __shfl(u_l, i + 8 + o8);
    int u2 = __shfl(u_l, i + 16 + o8);
    int u3 = __shfl(u_l, i + 24 + o8);
    uint4 p0 = *(const uint4*)(z + (size_t)u0 * 64 + fo);
    uint4 p1 = *(const uint4*)(z + (size_t)u1 * 64 + fo);
    uint4 p2 = *(const uint4*)(z + (size_t)u2 * 64 + fo);
    uint4 p3 = *(const uint4*)(z + (size_t)u3 * 64 + fo);
    acc8(a, p0); acc8(a, p1); acc8(a, p2); acc8(a, p3);
  }
  for (; i + 16 <= c; i += 16) {        // 16 edges, 2 loads
    int u0 = __shfl(u_l, i + o8);
    int u1 = __shfl(u_l, i + 8 + o8);
    uint4 p0 = *(const uint4*)(z + (size_t)u0 * 64 + fo);
    uint4 p1 = *(const uint4*)(z + (size_t)u1 * 64 + fo);
    acc8(a, p0); acc8(a, p1);
  }
  for (; i < c; i += 8) {               // masked tail
    int eidx = i + o8;
    int u = __shfl(u_l, eidx);
    uint4 p = *(const uint4*)(z + (size_t)u * 64 + fo);
    if (eidx >= c) { p.x = 0; p.y = 0; p.z = 0; p.w = 0; }
    acc8(a, p);
  }
  #pragma unroll
  for (int j = 0; j < 8; j++) {
    a[j] += __shfl_xor(a[j], 8);
    a[j] += __shfl_xor(a[j], 16);
    a[j] += __shfl_xor(a[j], 32);
  }
  if (lane < 8) {
    float sv = sin_[v];
    uint4 o;
    o.x = (unsigned)f2bf(sv * a[0]) | ((unsigned)f2bf(sv * a[1]) << 16);
    o.y = (unsigned)f2bf(sv * a[2]) | ((unsigned)f2bf(sv * a[3]) << 16);
    o.z = (unsigned)f2bf(sv * a[4]) | ((unsigned)f2bf(sv * a[5]) << 16);
    o.w = (unsigned)f2bf(sv * a[6]) | ((unsigned)f2bf(sv * a[7]) << 16);
    *(uint4*)(aggz + (size_t)v * 64 + fo) = o;
  }
}

extern "C" void kernel_launch(void* const* d_in, const int* in_sizes, int n_in,
                              void* d_out, int out_size, void* d_ws, size_t ws_size,
                              hipStream_t stream) {
  const float* features = (const float*)d_in[0];
  const int*   src      = (const int*)d_in[1];
  const int*   dst      = (const int*)d_in[2];
  const float* eps      = (const float*)d_in[3];
  const float* W1       = (const float*)d_in[4];
  const float* b1       = (const float*)d_in[5];
  const float* W2       = (const float*)d_in[6];
  const float* b2       = (const float*)d_in[7];
  const float* W3       = (const float*)d_in[8];
  const float* b3       = (const float*)d_in[9];
  const int E = in_sizes[1];
  const int N = in_sizes[3] / 64;   // eps is N x 64
  float* out = (float*)d_out;

  const int NFB = (N + 255) >> FBSH;                  // fine buckets (256 nodes)
  const int cap2 = ((E / NFB) + 2048 + 255) & ~255;   // records per bucket region

  // workspace (~78 MB): two aliased N*256-byte feature regions
  char* ws = (char*)d_ws;
  int* cnt    = (int*)ws;            ws += (size_t)N * 4;
  int* bcd    = (int*)ws;            ws += (size_t)NFB * 4;  // dst-bucket counts
  int* bcs    = (int*)ws;            ws += (size_t)NFB * 4;  // src-bucket counts
  int* ebuf   = (int*)ws;            ws += (size_t)N * MAXD * 4;
  float* sout = (float*)ws;          ws += (size_t)N * 4;
  float* sin_ = (float*)ws;          ws += (size_t)N * 4;
  short* W1p  = (short*)ws;          ws += 128 * 256 * 2;
  short* W2p  = (short*)ws;          ws += 256 * 128 * 2;
  short* W3p  = (short*)ws;          ws += 64 * 128 * 2;
  char* R1    = ws;                  ws += (size_t)N * 256;  // xb -> hwb -> aggz
  char* R2    = ws;                  ws += (size_t)N * 256;  // bktd/srec -> agg1 -> z

  unsigned short* xb    = (unsigned short*)R1;  // N x 128 bf16 (sout-scaled)
  unsigned short* hwb   = (unsigned short*)R1;  // N x 128 bf16 (xb dead)
  unsigned short* aggzb = (unsigned short*)R1;  // N x 64  bf16 (hwb dead)
  unsigned short* agg1b = (unsigned short*)R2;  // N x 128 bf16
  unsigned short* zb    = (unsigned short*)R2;  // N x 64  bf16 (agg1 dead, sout-scaled)
  // bucket records (~12MB) alias R2: dead before agg1b is written
  int* bktd = (int*)R2;                                     // NFB*cap2 4B records
  unsigned char* srec = (unsigned char*)(R2 + (size_t)NFB * cap2 * 4);

  // h (N x 256 bf16 = 51.2MB) lives in out[0..128N) floats; dead before recon
  unsigned short* h     = (unsigned short*)out;
  float* recon          = out;
  float* mean_out       = out + (size_t)N * 128;
  float* logvar_out     = out + (size_t)N * 192;

  hipMemsetAsync(bcd, 0, (size_t)NFB * 8, stream);   // bucket counters only

  const size_t shA = (size_t)4 * NFB * 4;
  k_bucket2<<<(E + 256 * EPT - 1) / (256 * EPT), 256, shA, stream>>>(
      src, dst, bcd, bcs, bktd, srec, E, NFB, cap2);
  k_csrdeg<<<NFB, 256, 0, stream>>>(bktd, bcd, srec, bcs, cnt, sin_, sout,
                                    ebuf, N, cap2);
  k_cvt<<<((N * 128 / 4) + 255) / 256, 256, 0, stream>>>(features, sout, xb, N * 128);
  k_wrepack_all<<<36, 256, 0, stream>>>(W1, W2, W3, W1p, W2p, W3p);

  // gconv1: row-sum SpMM(xb) -> agg1b; GEMM 128->256 +b1, relu, x sout -> h
  k_spmm128v<<<(N + 3) / 4, 256, 0, stream>>>(xb, ebuf, cnt, sin_, agg1b, N);
  k_gemm_mfma<128, 256, true, true, true, true>
      <<<(N + 63) / 64, 256, 0, stream>>>(agg1b, W1p, b1, sout, h, N);

  // gconv2: GEMM 256->128 (h @ W2 -> hwb), row-sum SpMM +b2, split, z(bf16)
  k_gemm_mfma<256, 128, false, false, true, false>
      <<<(N + 63) / 64, 256, 0, stream>>>(h, W2p, nullptr, nullptr, hwb, N);
  k_spmm2v<<<(N + 3) / 4, 256, 0, stream>>>(hwb, ebuf, cnt, sout, sin_, b2, eps,
                                            mean_out, logvar_out, zb, N);

  // gconv3: row-sum SpMM(zb) -> aggzb; GEMM 64->128 +b3 -> recon
  k_spmm64v<<<(N + 3) / 4, 256, 0, stream>>>(zb, ebuf, cnt, sin_, aggzb, N);
  k_gemm_mfma<64, 128, false, true, false, false>
      <<<(N + 63) / 64, 256, 0, stream>>>(aggzb, W3p, b3, nullptr, recon, N);
}

// Round 9
// 501.374 us; speedup vs baseline: 1.2199x; 1.0368x over previous
//
#include <hip/hip_runtime.h>
#include <math.h>

// Graph VAE forward, bf16 edition.
//   SpMM at the narrow dim (gconv2 does GEMM first), pull-style padded CSR.
//   Weight-free row-sum SpMM (sout folded into rows), dwordx4 gathers.
//   SpMM is at the L3 random-gather fabric ceiling (~3.9 TB/s, r8) - frozen.
//   This round: gemm1+gemm2 fused (k_gemm12). h-tile (16x256 bf16) staged in
//     per-wave LDS between the two MFMA chains; h never touches HBM
//     (saves ~100MB roundtrip + scalar-store epilogue; launches 10 -> 9).
//   CSR build: LDS-bucketed two-phase, no per-edge global atomics.

#define MAXD 64   // padded per-node in-edge capacity; deg ~ Poisson(16)
#define FBSH 8    // 256 nodes per fine bucket (== blockDim of k_csrdeg)
#define EPT  16   // edges per thread in k_bucket2 (4096 per WG)

typedef short short8 __attribute__((ext_vector_type(8)));
typedef float f32x4 __attribute__((ext_vector_type(4)));

__device__ __forceinline__ unsigned short f2bf(float f) {
  union { float f; unsigned u; } c; c.f = f;
  unsigned r = c.u + 0x7FFF + ((c.u >> 16) & 1);   // RNE
  return (unsigned short)(r >> 16);
}
__device__ __forceinline__ float bf2f(unsigned short b) {
  return __builtin_bit_cast(float, (unsigned)b << 16);
}
// accumulate 8 bf16 (packed in uint4) into a[0..7]
__device__ __forceinline__ void acc8(float* a, uint4 p) {
  a[0] += __builtin_bit_cast(float, p.x << 16);
  a[1] += __builtin_bit_cast(float, p.x & 0xFFFF0000u);
  a[2] += __builtin_bit_cast(float, p.y << 16);
  a[3] += __builtin_bit_cast(float, p.y & 0xFFFF0000u);
  a[4] += __builtin_bit_cast(float, p.z << 16);
  a[5] += __builtin_bit_cast(float, p.z & 0xFFFF0000u);
  a[6] += __builtin_bit_cast(float, p.w << 16);
  a[7] += __builtin_bit_cast(float, p.w & 0xFFFF0000u);
}

// ---- phase A: two-level bucket, all per-edge counting in LDS -----------
__global__ __launch_bounds__(256) void k_bucket2(const int* __restrict__ src,
    const int* __restrict__ dst, int* __restrict__ bcd, int* __restrict__ bcs,
    int* __restrict__ bktd, unsigned char* __restrict__ srec,
    int E, int NFB, int cap2) {
  extern __shared__ int sh[];            // 4*NFB ints
  int* lcd = sh;                         // dst-bucket counts
  int* lbd = sh + NFB;                   // dst-bucket running offsets
  int* lcs = sh + 2 * NFB;               // src-bucket counts
  int* lbs = sh + 3 * NFB;               // src-bucket running offsets
  int tid = threadIdx.x;
  for (int i = tid; i < 4 * NFB; i += 256) sh[i] = 0;
  __syncthreads();
  int e0 = blockIdx.x * (256 * EPT);
  // pass 1: count per fine bucket (LDS atomics only)
  #pragma unroll 4
  for (int j = 0; j < EPT; j++) {
    int e = e0 + j * 256 + tid;
    if (e < E) {
      int d = dst[e]; atomicAdd(&lcd[d >> FBSH], 1);
      int s = src[e]; atomicAdd(&lcs[s >> FBSH], 1);
    }
  }
  __syncthreads();
  // reserve global chunks: one atomic per (WG, touched bucket)
  for (int fb = tid; fb < NFB; fb += 256) {
    int c = lcd[fb];
    if (c) lbd[fb] = atomicAdd(&bcd[fb], c);
    int cs = lcs[fb];
    if (cs) lbs[fb] = atomicAdd(&bcs[fb], cs);
  }
  __syncthreads();
  // pass 2: re-read edges (L1/L2 hot), place records
  #pragma unroll 4
  for (int j = 0; j < EPT; j++) {
    int e = e0 + j * 256 + tid;
    if (e < E) {
      int d = dst[e]; int s = src[e];
      int fbd = d >> FBSH;
      int od = atomicAdd(&lbd[fbd], 1);
      if (od < cap2) bktd[(size_t)fbd * cap2 + od] = ((d & 255) << 24) | s;
      int fbs = s >> FBSH;
      int os = atomicAdd(&lbs[fbs], 1);
      if (os < cap2) srec[(size_t)fbs * cap2 + os] = (unsigned char)(s & 255);
    }
  }
}

// ---- phase C: per-bucket CSR fill + in/out-degree scales ---------------
__global__ __launch_bounds__(256) void k_csrdeg(const int* __restrict__ bktd,
    const int* __restrict__ bcd, const unsigned char* __restrict__ srec,
    const int* __restrict__ bcs, int* __restrict__ cnt, float* __restrict__ sin_,
    float* __restrict__ sout, int* __restrict__ ebuf, int N, int cap2) {
  __shared__ int lcnt[256];
  __shared__ int lh[256];
  int fb = blockIdx.x;
  int tid = threadIdx.x;
  lcnt[tid] = 0;
  lh[tid] = 0;
  __syncthreads();
  // C1: CSR fill from dst-bucket records
  {
    int m = bcd[fb]; m = m < cap2 ? m : cap2;
    const int* rec = bktd + (size_t)fb * cap2;
    for (int i0 = tid * 4; i0 < m; i0 += 1024) {
      if (i0 + 4 <= m) {
        int4 r = *(const int4*)(rec + i0);
        int dl, s, p;
        dl = (unsigned)r.x >> 24; s = r.x & 0xFFFFFF;
        p = atomicAdd(&lcnt[dl], 1);
        if (p < MAXD) ebuf[((size_t)(fb << FBSH) + dl) * MAXD + p] = s;
        dl = (unsigned)r.y >> 24; s = r.y & 0xFFFFFF;
        p = atomicAdd(&lcnt[dl], 1);
        if (p < MAXD) ebuf[((size_t)(fb << FBSH) + dl) * MAXD + p] = s;
        dl = (unsigned)r.z >> 24; s = r.z & 0xFFFFFF;
        p = atomicAdd(&lcnt[dl], 1);
        if (p < MAXD) ebuf[((size_t)(fb << FBSH) + dl) * MAXD + p] = s;
        dl = (unsigned)r.w >> 24; s = r.w & 0xFFFFFF;
        p = atomicAdd(&lcnt[dl], 1);
        if (p < MAXD) ebuf[((size_t)(fb << FBSH) + dl) * MAXD + p] = s;
      } else {
        for (int k = i0; k < m; k++) {
          int r = rec[k];
          int dl = (unsigned)r >> 24; int s = r & 0xFFFFFF;
          int p = atomicAdd(&lcnt[dl], 1);
          if (p < MAXD) ebuf[((size_t)(fb << FBSH) + dl) * MAXD + p] = s;
        }
      }
    }
  }
  // C2: out-degree histogram from src-bucket records
  {
    int m = bcs[fb]; m = m < cap2 ? m : cap2;
    const unsigned char* rec = srec + (size_t)fb * cap2;
    for (int i0 = tid * 4; i0 < m; i0 += 1024) {
      if (i0 + 4 <= m) {
        uchar4 r = *(const uchar4*)(rec + i0);
        atomicAdd(&lh[r.x], 1); atomicAdd(&lh[r.y], 1);
        atomicAdd(&lh[r.z], 1); atomicAdd(&lh[r.w], 1);
      } else {
        for (int k = i0; k < m; k++) atomicAdd(&lh[rec[k]], 1);
      }
    }
  }
  __syncthreads();
  int node = (fb << FBSH) + tid;
  if (node < N) {
    int c = lcnt[tid];
    cnt[node] = c;                       // true in-degree; spmm clamps at MAXD
    sin_[node] = rsqrtf((float)(c < 1 ? 1 : c));
    int d = lh[tid];
    sout[node] = rsqrtf((float)(d < 1 ? 1 : d));
  }
}

// ---- fp32 -> bf16 convert, row pre-scaled by sout[row] ----------------
__global__ __launch_bounds__(256) void k_cvt(const float* __restrict__ in,
    const float* __restrict__ sout, unsigned short* __restrict__ out, int n) {
  int i = (blockIdx.x * 256 + threadIdx.x) * 4;
  if (i >= n) return;
  float s = sout[i >> 7];                // D=128; 4 elems never cross a row
  float4 f = *(const float4*)(in + i);
  unsigned lo = (unsigned)f2bf(s * f.x) | ((unsigned)f2bf(s * f.y) << 16);
  unsigned hi = (unsigned)f2bf(s * f.z) | ((unsigned)f2bf(s * f.w) << 16);
  uint2 o; o.x = lo; o.y = hi;
  *(uint2*)(out + i) = o;
}

// ---- repack W[K][OC] fp32 -> bf16 B-fragment layout (all 3 in one) ----
template <int K, int OC>
__device__ __forceinline__ void wrepack_body(const float* __restrict__ W,
    short* __restrict__ Wp, int t) {
  constexpr int KC = K / 32;
  int lane = t & 63;
  int kc = (t >> 6) % KC;
  int nt = t / (KC * 64);
  int n = nt * 16 + (lane & 15);
  int k0 = kc * 32 + ((lane >> 4) * 8);
  short8 v;
  #pragma unroll
  for (int j = 0; j < 8; j++) v[j] = (short)f2bf(W[(size_t)(k0 + j) * OC + n]);
  *(short8*)(Wp + (size_t)t * 8) = v;
}

__global__ __launch_bounds__(256) void k_wrepack_all(
    const float* __restrict__ W1, const float* __restrict__ W2,
    const float* __restrict__ W3, short* __restrict__ W1p,
    short* __restrict__ W2p, short* __restrict__ W3p) {
  int t = blockIdx.x * 256 + threadIdx.x;
  if (t < 4096) wrepack_body<128, 256>(W1, W1p, t);             // 16*4*64
  else if (t < 8192) wrepack_body<256, 128>(W2, W2p, t - 4096); // 8*8*64
  else if (t < 9216) wrepack_body<64, 128>(W3, W3p, t - 8192);  // 8*2*64
}

// ---- fused GEMM1+GEMM2: hwb = relu(agg1@W1+b1)*sout @ W2 --------------
//   h-tile (16x256 bf16) staged in per-wave LDS; h never hits HBM.
//   LDS row stride 264 ushorts = 528B == 16 mod 128 -> 2-way bank alias
//   on ds_read_b128 A-fragments (free).
__global__ __launch_bounds__(256) void k_gemm12(
    const unsigned short* __restrict__ A,   // agg1b N x 128 bf16
    const short* __restrict__ W1p, const short* __restrict__ W2p,
    const float* __restrict__ b1, const float* __restrict__ srow,
    unsigned short* __restrict__ hwb, int N) {
  __shared__ unsigned short lh[4][16][264];
  int lane = threadIdx.x & 63;
  int wv = threadIdx.x >> 6;
  int m0 = (blockIdx.x * 4 + wv) * 16;
  bool active = m0 < N;
  int mrow = m0 + (lane & 15);
  if (mrow >= N) mrow = N - 1;            // clamp loads; stores predicated
  int q = lane >> 4;
  int col0 = lane & 15;
  int rbl = q * 4;                        // local C/D row base
  if (active) {
    short8 av[4];
    #pragma unroll
    for (int kc = 0; kc < 4; kc++)
      av[kc] = *(const short8*)(A + (size_t)mrow * 128 + kc * 32 + q * 8);
    float sr[4];
    #pragma unroll
    for (int r = 0; r < 4; r++) {
      int row = m0 + rbl + r;
      sr[r] = (row < N) ? srow[row] : 1.f;
    }
    #pragma unroll
    for (int nt = 0; nt < 16; nt++) {
      f32x4 acc = {0.f, 0.f, 0.f, 0.f};
      #pragma unroll
      for (int kc = 0; kc < 4; kc++) {
        short8 bv = *(const short8*)(W1p + ((size_t)(nt * 4 + kc) * 64 + lane) * 8);
        acc = __builtin_amdgcn_mfma_f32_16x16x32_bf16(av[kc], bv, acc, 0, 0, 0);
      }
      int col = nt * 16 + col0;
      float bb = b1[col];
      #pragma unroll
      for (int r = 0; r < 4; r++)
        lh[wv][rbl + r][col] = f2bf(fmaxf(acc[r] + bb, 0.f) * sr[r]);
    }
  }
  __syncthreads();                        // order h-writes before h-reads
  if (!active) return;
  short8 av2[8];
  #pragma unroll
  for (int kc = 0; kc < 8; kc++)
    av2[kc] = *(const short8*)&lh[wv][col0][kc * 32 + q * 8];
  #pragma unroll
  for (int nt = 0; nt < 8; nt++) {
    f32x4 acc = {0.f, 0.f, 0.f, 0.f};
    #pragma unroll
    for (int kc = 0; kc < 8; kc++) {
      short8 bv = *(const short8*)(W2p + ((size_t)(nt * 8 + kc) * 64 + lane) * 8);
      acc = __builtin_amdgcn_mfma_f32_16x16x32_bf16(av2[kc], bv, acc, 0, 0, 0);
    }
    int col = nt * 16 + col0;
    #pragma unroll
    for (int r = 0; r < 4; r++) {
      int row = m0 + rbl + r;
      if (row < N) hwb[(size_t)row * 128 + col] = f2bf(acc[r]);
    }
  }
}

// ---- MFMA GEMM: C[N,OC] = A[N,K](bf16) @ Wp (+bias) -------------------
template <int K, int OC, bool BIAS>
__global__ __launch_bounds__(256) void k_gemm_mfma(
    const unsigned short* __restrict__ A, const short* __restrict__ Wp,
    const float* __restrict__ bias, float* __restrict__ Cout, int N) {
  constexpr int KC = K / 32;
  constexpr int NT = OC / 16;
  int lane = threadIdx.x & 63;
  int wv = threadIdx.x >> 6;
  int m0 = (blockIdx.x * 4 + wv) * 16;
  if (m0 >= N) return;
  int mrow = m0 + (lane & 15);
  if (mrow >= N) mrow = N - 1;          // clamp loads; stores predicated
  int q = lane >> 4;
  short8 av[KC];
  #pragma unroll
  for (int kc = 0; kc < KC; kc++)
    av[kc] = *(const short8*)(A + (size_t)mrow * K + kc * 32 + q * 8);
  int col0 = lane & 15;
  int rbase = m0 + q * 4;               // C/D: col=lane&15, row=(lane>>4)*4+r
  #pragma unroll
  for (int nt = 0; nt < NT; nt++) {
    f32x4 acc = {0.f, 0.f, 0.f, 0.f};
    #pragma unroll
    for (int kc = 0; kc < KC; kc++) {
      short8 bv = *(const short8*)(Wp + ((size_t)(nt * KC + kc) * 64 + lane) * 8);
      acc = __builtin_amdgcn_mfma_f32_16x16x32_bf16(av[kc], bv, acc, 0, 0, 0);
    }
    int col = nt * 16 + col0;
    float bb = BIAS ? bias[col] : 0.f;
    #pragma unroll
    for (int r = 0; r < 4; r++) {
      int row = rbase + r;
      if (row < N) Cout[(size_t)row * OC + col] = acc[r] + bb;
    }
  }
}

// ---- SpMM 128-wide row-sum: 16 lanes/row, 4 quarter-waves -------------
__global__ __launch_bounds__(256) void k_spmm128v(const unsigned short* __restrict__ x,
    const int* __restrict__ ebuf, const int* __restrict__ cnt,
    const float* __restrict__ sin_, unsigned short* __restrict__ out, int N) {
  int lane = threadIdx.x & 63;
  int v = blockIdx.x * 4 + (threadIdx.x >> 6);
  if (v >= N) return;
  v = __builtin_amdgcn_readfirstlane(v);
  int c = cnt[v]; c = c < MAXD ? c : MAXD;
  const int* el = ebuf + (size_t)v * MAXD;
  int u_l = (lane < c) ? el[lane] : 0;
  int q = lane >> 4;
  int fo = (lane & 15) * 8;             // ushort offset within row
  float a[8] = {0, 0, 0, 0, 0, 0, 0, 0};
  int i = 0;
  for (; i + 16 <= c; i += 16) {        // 16 edges, 4 loads in flight
    int u0 = __shfl(u_l, i + q);
    int u1 = __shfl(u_l, i + 4 + q);
    int u2 = __shfl(u_l, i + 8 + q);
    int u3 = __shfl(u_l, i + 12 + q);
    uint4 p0 = *(const uint4*)(x + (size_t)u0 * 128 + fo);
    uint4 p1 = *(const uint4*)(x + (size_t)u1 * 128 + fo);
    uint4 p2 = *(const uint4*)(x + (size_t)u2 * 128 + fo);
    uint4 p3 = *(const uint4*)(x + (size_t)u3 * 128 + fo);
    acc8(a, p0); acc8(a, p1); acc8(a, p2); acc8(a, p3);
  }
  for (; i + 8 <= c; i += 8) {          // 8 edges, 2 loads
    int u0 = __shfl(u_l, i + q);
    int u1 = __shfl(u_l, i + 4 + q);
    uint4 p0 = *(const uint4*)(x + (size_t)u0 * 128 + fo);
    uint4 p1 = *(const uint4*)(x + (size_t)u1 * 128 + fo);
    acc8(a, p0); acc8(a, p1);
  }
  for (; i < c; i += 4) {               // masked tail: up to 4 edges
    int eidx = i + q;
    int u = __shfl(u_l, eidx);
    uint4 p = *(const uint4*)(x + (size_t)u * 128 + fo);
    if (eidx >= c) { p.x = 0; p.y = 0; p.z = 0; p.w = 0; }
    acc8(a, p);
  }
  #pragma unroll
  for (int j = 0; j < 8; j++) {
    a[j] += __shfl_xor(a[j], 16);
    a[j] += __shfl_xor(a[j], 32);
  }
  if (lane < 16) {
    float sv = sin_[v];
    uint4 o;
    o.x = (unsigned)f2bf(sv * a[0]) | ((unsigned)f2bf(sv * a[1]) << 16);
    o.y = (unsigned)f2bf(sv * a[2]) | ((unsigned)f2bf(sv * a[3]) << 16);
    o.z = (unsigned)f2bf(sv * a[4]) | ((unsigned)f2bf(sv * a[5]) << 16);
    o.w = (unsigned)f2bf(sv * a[6]) | ((unsigned)f2bf(sv * a[7]) << 16);
    *(uint4*)(out + (size_t)v * 128 + fo) = o;
  }
}

// ---- SpMM 128-wide row-sum + epilogue: +b2, split, z=sout*(eps*e^.5lv+m)
__global__ __launch_bounds__(256) void k_spmm2v(const unsigned short* __restrict__ hw,
    const int* __restrict__ ebuf, const int* __restrict__ cnt,
    const float* __restrict__ sout, const float* __restrict__ sin_,
    const float* __restrict__ b2, const float* __restrict__ eps,
    float* __restrict__ mean_out, float* __restrict__ logvar_out,
    unsigned short* __restrict__ z, int N) {
  int lane = threadIdx.x & 63;
  int v = blockIdx.x * 4 + (threadIdx.x >> 6);
  if (v >= N) return;
  v = __builtin_amdgcn_readfirstlane(v);
  int c = cnt[v]; c = c < MAXD ? c : MAXD;
  const int* el = ebuf + (size_t)v * MAXD;
  int u_l = (lane < c) ? el[lane] : 0;
  int q = lane >> 4;
  int fo = (lane & 15) * 8;
  float a[8] = {0, 0, 0, 0, 0, 0, 0, 0};
  int i = 0;
  for (; i + 16 <= c; i += 16) {
    int u0 = __shfl(u_l, i + q);
    int u1 = __shfl(u_l, i + 4 + q);
    int u2 = __shfl(u_l, i + 8 + q);
    int u3 = __shfl(u_l, i + 12 + q);
    uint4 p0 = *(const uint4*)(hw + (size_t)u0 * 128 + fo);
    uint4 p1 = *(const uint4*)(hw + (size_t)u1 * 128 + fo);
    uint4 p2 = *(const uint4*)(hw + (size_t)u2 * 128 + fo);
    uint4 p3 = *(const uint4*)(hw + (size_t)u3 * 128 + fo);
    acc8(a, p0); acc8(a, p1); acc8(a, p2); acc8(a, p3);
  }
  for (; i + 8 <= c; i += 8) {
    int u0 = __shfl(u_l, i + q);
    int u1 = __shfl(u_l, i + 4 + q);
    uint4 p0 = *(const uint4*)(hw + (size_t)u0 * 128 + fo);
    uint4 p1 = *(const uint4*)(hw + (size_t)u1 * 128 + fo);
    acc8(a, p0); acc8(a, p1);
  }
  for (; i < c; i += 4) {
    int eidx = i + q;
    int u = __shfl(u_l, eidx);
    uint4 p = *(const uint4*)(hw + (size_t)u * 128 + fo);
    if (eidx >= c) { p.x = 0; p.y = 0; p.z = 0; p.w = 0; }
    acc8(a, p);
  }
  #pragma unroll
  for (int j = 0; j < 8; j++) {
    a[j] += __shfl_xor(a[j], 16);
    a[j] += __shfl_xor(a[j], 32);
  }
  // m[j] = sin[v]*a[j] + b2[fo+j]; features 0..63 = mean, 64..127 = logvar
  float sv = sin_[v];
  float4 blo = *(const float4*)(b2 + fo);
  float4 bhi = *(const float4*)(b2 + fo + 4);
  float m[8];
  m[0] = fmaf(sv, a[0], blo.x); m[1] = fmaf(sv, a[1], blo.y);
  m[2] = fmaf(sv, a[2], blo.z); m[3] = fmaf(sv, a[3], blo.w);
  m[4] = fmaf(sv, a[4], bhi.x); m[5] = fmaf(sv, a[5], bhi.y);
  m[6] = fmaf(sv, a[6], bhi.z); m[7] = fmaf(sv, a[7], bhi.w);
  float lv[8];
  #pragma unroll
  for (int j = 0; j < 8; j++) lv[j] = __shfl_xor(m[j], 8);  // pair k <-> k+8
  int k = lane & 15;
  if (lane < 16) {
    if (k < 8) {
      *(float4*)(mean_out + (size_t)v * 64 + k * 8) =
          make_float4(m[0], m[1], m[2], m[3]);
      *(float4*)(mean_out + (size_t)v * 64 + k * 8 + 4) =
          make_float4(m[4], m[5], m[6], m[7]);
      float so = sout[v];
      float4 e0 = *(const float4*)(eps + (size_t)v * 64 + k * 8);
      float4 e1 = *(const float4*)(eps + (size_t)v * 64 + k * 8 + 4);
      float z0 = so * fmaf(e0.x, expf(0.5f * lv[0]), m[0]);
      float z1 = so * fmaf(e0.y, expf(0.5f * lv[1]), m[1]);
      float z2 = so * fmaf(e0.z, expf(0.5f * lv[2]), m[2]);
      float z3 = so * fmaf(e0.w, expf(0.5f * lv[3]), m[3]);
      float z4 = so * fmaf(e1.x, expf(0.5f * lv[4]), m[4]);
      float z5 = so * fmaf(e1.y, expf(0.5f * lv[5]), m[5]);
      float z6 = so * fmaf(e1.z, expf(0.5f * lv[6]), m[6]);
      float z7 = so * fmaf(e1.w, expf(0.5f * lv[7]), m[7]);
      uint4 o;
      o.x = (unsigned)f2bf(z0) | ((unsigned)f2bf(z1) << 16);
      o.y = (unsigned)f2bf(z2) | ((unsigned)f2bf(z3) << 16);
      o.z = (unsigned)f2bf(z4) | ((unsigned)f2bf(z5) << 16);
      o.w = (unsigned)f2bf(z6) | ((unsigned)f2bf(z7) << 16);
      *(uint4*)(z + (size_t)v * 64 + k * 8) = o;
    } else {
      *(float4*)(logvar_out + (size_t)v * 64 + (k - 8) * 8) =
          make_float4(m[0], m[1], m[2], m[3]);
      *(float4*)(logvar_out + (size_t)v * 64 + (k - 8) * 8 + 4) =
          make_float4(m[4], m[5], m[6], m[7]);
    }
  }
}

// ---- SpMM 64-wide row-sum: 8 lanes/row, 8 edges per load --------------
__global__ __launch_bounds__(256) void k_spmm64v(const unsigned short* __restrict__ z,
    const int* __restrict__ ebuf, const int* __restrict__ cnt,
    const float* __restrict__ sin_, unsigned short* __restrict__ aggz, int N) {
  int lane = threadIdx.x & 63;
  int v = blockIdx.x * 4 + (threadIdx.x >> 6);
  if (v >= N) return;
  v = __builtin_amdgcn_readfirstlane(v);
  int c = cnt[v]; c = c < MAXD ? c : MAXD;
  const int* el = ebuf + (size_t)v * MAXD;
  int u_l = (lane < c) ? el[lane] : 0;
  int o8 = lane >> 3;
  int fo = (lane & 7) * 8;
  float a[8] = {0, 0, 0, 0, 0, 0, 0, 0};
  int i = 0;
  for (; i + 32 <= c; i += 32) {        // 32 edges, 4 loads in flight
    int u0 = __shfl(u_l, i + o8);
    int u1 = __shfl(u_l, i + 8 + o8);
    int u2 = __shfl(u_l, i + 16 + o8);
    int u3 = __shfl(u_l, i + 24 + o8);
    uint4 p0 = *(const uint4*)(z + (size_t)u0 * 64 + fo);
    uint4 p1 = *(const uint4*)(z + (size_t)u1 * 64 + fo);
    uint4 p2 = *(const uint4*)(z + (size_t)u2 * 64 + fo);
    uint4 p3 = *(const uint4*)(z + (size_t)u3 * 64 + fo);
    acc8(a, p0); acc8(a, p1); acc8(a, p2); acc8(a, p3);
  }
  for (; i + 16 <= c; i += 16) {        // 16 edges, 2 loads
    int u0 = __shfl(u_l, i + o8);
    int u1 = __shfl(u_l, i + 8 + o8);
    uint4 p0 = *(const uint4*)(z + (size_t)u0 * 64 + fo);
    uint4 p1 = *(const uint4*)(z + (size_t)u1 * 64 + fo);
    acc8(a, p0); acc8(a, p1);
  }
  for (; i < c; i += 8) {               // masked tail
    int eidx = i + o8;
    int u = __shfl(u_l, eidx);
    uint4 p = *(const uint4*)(z + (size_t)u * 64 + fo);
    if (eidx >= c) { p.x = 0; p.y = 0; p.z = 0; p.w = 0; }
    acc8(a, p);
  }
  #pragma unroll
  for (int j = 0; j < 8; j++) {
    a[j] += __shfl_xor(a[j], 8);
    a[j] += __shfl_xor(a[j], 16);
    a[j] += __shfl_xor(a[j], 32);
  }
  if (lane < 8) {
    float sv = sin_[v];
    uint4 o;
    o.x = (unsigned)f2bf(sv * a[0]) | ((unsigned)f2bf(sv * a[1]) << 16);
    o.y = (unsigned)f2bf(sv * a[2]) | ((unsigned)f2bf(sv * a[3]) << 16);
    o.z = (unsigned)f2bf(sv * a[4]) | ((unsigned)f2bf(sv * a[5]) << 16);
    o.w = (unsigned)f2bf(sv * a[6]) | ((unsigned)f2bf(sv * a[7]) << 16);
    *(uint4*)(aggz + (size_t)v * 64 + fo) = o;
  }
}

extern "C" void kernel_launch(void* const* d_in, const int* in_sizes, int n_in,
                              void* d_out, int out_size, void* d_ws, size_t ws_size,
                              hipStream_t stream) {
  const float* features = (const float*)d_in[0];
  const int*   src      = (const int*)d_in[1];
  const int*   dst      = (const int*)d_in[2];
  const float* eps      = (const float*)d_in[3];
  const float* W1       = (const float*)d_in[4];
  const float* b1       = (const float*)d_in[5];
  const float* W2       = (const float*)d_in[6];
  const float* b2       = (const float*)d_in[7];
  const float* W3       = (const float*)d_in[8];
  const float* b3       = (const float*)d_in[9];
  const int E = in_sizes[1];
  const int N = in_sizes[3] / 64;   // eps is N x 64
  float* out = (float*)d_out;

  const int NFB = (N + 255) >> FBSH;                  // fine buckets (256 nodes)
  const int cap2 = ((E / NFB) + 2048 + 255) & ~255;   // records per bucket region

  // workspace (~78 MB): two aliased N*256-byte feature regions
  char* ws = (char*)d_ws;
  int* cnt    = (int*)ws;            ws += (size_t)N * 4;
  int* bcd    = (int*)ws;            ws += (size_t)NFB * 4;  // dst-bucket counts
  int* bcs    = (int*)ws;            ws += (size_t)NFB * 4;  // src-bucket counts
  int* ebuf   = (int*)ws;            ws += (size_t)N * MAXD * 4;
  float* sout = (float*)ws;          ws += (size_t)N * 4;
  float* sin_ = (float*)ws;          ws += (size_t)N * 4;
  short* W1p  = (short*)ws;          ws += 128 * 256 * 2;
  short* W2p  = (short*)ws;          ws += 256 * 128 * 2;
  short* W3p  = (short*)ws;          ws += 64 * 128 * 2;
  char* R1    = ws;                  ws += (size_t)N * 256;  // xb -> hwb -> aggz
  char* R2    = ws;                  ws += (size_t)N * 256;  // bktd/srec -> agg1 -> z

  unsigned short* xb    = (unsigned short*)R1;  // N x 128 bf16 (sout-scaled)
  unsigned short* hwb   = (unsigned short*)R1;  // N x 128 bf16 (xb dead)
  unsigned short* aggzb = (unsigned short*)R1;  // N x 64  bf16 (hwb dead)
  unsigned short* agg1b = (unsigned short*)R2;  // N x 128 bf16
  unsigned short* zb    = (unsigned short*)R2;  // N x 64  bf16 (agg1 dead, sout-scaled)
  // bucket records (~12MB) alias R2: dead before agg1b is written
  int* bktd = (int*)R2;                                     // NFB*cap2 4B records
  unsigned char* srec = (unsigned char*)(R2 + (size_t)NFB * cap2 * 4);

  float* recon          = out;
  float* mean_out       = out + (size_t)N * 128;
  float* logvar_out     = out + (size_t)N * 192;

  hipMemsetAsync(bcd, 0, (size_t)NFB * 8, stream);   // bucket counters only

  const size_t shA = (size_t)4 * NFB * 4;
  k_bucket2<<<(E + 256 * EPT - 1) / (256 * EPT), 256, shA, stream>>>(
      src, dst, bcd, bcs, bktd, srec, E, NFB, cap2);
  k_csrdeg<<<NFB, 256, 0, stream>>>(bktd, bcd, srec, bcs, cnt, sin_, sout,
                                    ebuf, N, cap2);
  k_cvt<<<((N * 128 / 4) + 255) / 256, 256, 0, stream>>>(features, sout, xb, N * 128);
  k_wrepack_all<<<36, 256, 0, stream>>>(W1, W2, W3, W1p, W2p, W3p);

  // gconv1+gconv2 front: SpMM(xb) -> agg1b; fused GEMM 128->256->128 -> hwb
  k_spmm128v<<<(N + 3) / 4, 256, 0, stream>>>(xb, ebuf, cnt, sin_, agg1b, N);
  k_gemm12<<<(N + 63) / 64, 256, 0, stream>>>(agg1b, W1p, W2p, b1, sout, hwb, N);

  // gconv2 back: row-sum SpMM +b2, split, z(bf16)
  k_spmm2v<<<(N + 3) / 4, 256, 0, stream>>>(hwb, ebuf, cnt, sout, sin_, b2, eps,
                                            mean_out, logvar_out, zb, N);

  // gconv3: row-sum SpMM(zb) -> aggzb; GEMM 64->128 +b3 -> recon
  k_spmm64v<<<(N + 3) / 4, 256, 0, stream>>>(zb, ebuf, cnt, sin_, aggzb, N);
  k_gemm_mfma<64, 128, true>
      <<<(N + 63) / 64, 256, 0, stream>>>(aggzb, W3p, b3, recon, N);
}